// Round 1
// baseline (85965.509 us; speedup 1.0000x reference)
//
#include <hip/hip_runtime.h>
#include <hip/hip_bf16.h>
#include <cstdint>
#include <cstddef>

// Handwriting synthesis net: persistent dataflow pipeline.
// Groups: L1(50 wgs) -> PA attention(8) -> L2(80) -> L3(80) -> OUT(16), 234 wgs total.
// Flags: padded to 64B, atomicAdd-RMW polled (coherence-point reads, XCD-safe).
// ws requirement: ~101.5 MB.

constexpr int B_ = 64, T_ = 600, U_ = 50, H_ = 400, V_ = 77, K_ = 10, OUT_ = 121;
constexpr int G1 = 50, GPA = 8, G2 = 80, G3 = 80, GOUT = 16;
constexpr int NBLK = G1 + GPA + G2 + G3 + GOUT; // 234

// ws layout (float element offsets for fp32 region)
constexpr size_t HS1 = 0;                       // [2][B][H] ping-pong h state L1
constexpr size_t HS2 = HS1 + 2 * B_ * H_;
constexpr size_t HS3 = HS2 + 2 * B_ * H_;
constexpr size_t CS1 = HS3 + 2 * B_ * H_;       // [B][H] c state (in-place)
constexpr size_t CS2 = CS1 + B_ * H_;
constexpr size_t CS3 = CS2 + B_ * H_;
constexpr size_t KST = CS3 + B_ * H_;           // [B][K] kappa state
constexpr size_t F32_CNT = KST + B_ * K_;
constexpr size_t HIDSZ = (size_t)T_ * B_ * H_;  // bf16 elements per hid array
constexpr size_t HID1_B = ((F32_CNT * 4 + 255) / 256) * 256;
constexpr size_t HID2_B = HID1_B + HIDSZ * 2;
constexpr size_t HID3_B = HID2_B + HIDSZ * 2;
constexpr size_t FLAG_B = HID3_B + HIDSZ * 2;
// flag indices (each flag padded to 16 ints = 64B)
constexpr int FL1 = 0;
constexpr int FLPA = FL1 + T_ * G1;
constexpr int FL2 = FLPA + T_ * GPA;
constexpr int FL3 = FL2 + T_ * G2;
constexpr int NFLAGS = FL3 + T_ * G3;
constexpr int FPAD = 16;

struct P {
  const float *x, *tmask, *h0, *c0, *pwv, *pkap;
  const int *text;
  const float *wih1, *whh1, *bih1, *bhh1;
  const float *wih2, *whh2, *bih2, *bhh2;
  const float *wih3, *whh3, *bih3, *bhh3;
  const float *wwin, *bwin, *wout, *bout;
  float *out_y, *out_wv, *out_kap;
  float *ws;
  __hip_bfloat16 *hid1, *hid2, *hid3;
  int *flags;
};

__device__ __forceinline__ void poll_n(int* f, int n) {
  for (int i = threadIdx.x; i < n; i += 256) {
    while (atomicAdd(f + (size_t)i * FPAD, 0) == 0) __builtin_amdgcn_s_sleep(2);
  }
}
__device__ __forceinline__ void acq() { __builtin_amdgcn_fence(__ATOMIC_ACQUIRE, "agent"); }
__device__ __forceinline__ void rel() { __builtin_amdgcn_fence(__ATOMIC_RELEASE, "agent"); }
__device__ __forceinline__ float sigm(float x) { return 1.f / (1.f + __expf(-x)); }

// ---------------- LSTM layer group ----------------
template <int L>
__device__ void lstm_role(const P& p, int wg, float* smem) {
  const int tid = threadIdx.x;
  constexpr int NU = (L == 1) ? 8 : 5;
  constexpr int NCOL = 4 * NU;                 // 32 or 20
  constexpr int INCH = (L == 1) ? 1 : 6;       // input-feature chunks of 80
  constexpr int NCH = INCH + 5;                // + 5 chunks of recurrent h
  constexpr int INW = INCH * 80;               // wih row width
  const int u0 = wg * NU;
  const float* wih = (L == 1) ? p.wih1 : (L == 2) ? p.wih2 : p.wih3;
  const float* whh = (L == 1) ? p.whh1 : (L == 2) ? p.whh2 : p.whh3;
  const float* bih = (L == 1) ? p.bih1 : (L == 2) ? p.bih2 : p.bih3;
  const float* bhh = (L == 1) ? p.bhh1 : (L == 2) ? p.bhh2 : p.bhh3;
  float* hs = p.ws + ((L == 1) ? HS1 : (L == 2) ? HS2 : HS3);
  float* cs = p.ws + ((L == 1) ? CS1 : (L == 2) ? CS2 : CS3);
  const __hip_bfloat16* hin = (L == 2) ? p.hid1 : p.hid2;  // unused for L1
  __hip_bfloat16* hout = (L == 1) ? p.hid1 : (L == 2) ? p.hid2 : p.hid3;
  float* gsm = smem + 64 * 84;

  const int tc = tid & 15, tb = tid >> 4;
  const int cb = tc * 2;  // local col base

  for (int t = 0; t < T_; ++t) {
    if (L == 1) {
      if (t > 0) poll_n(p.flags + (size_t)(FLPA + (t - 1) * GPA) * FPAD - (size_t)threadIdx.x * 0, GPA);
    } else if (L == 2) {
      poll_n(p.flags + (size_t)(FLPA + t * GPA) * FPAD / FPAD * FPAD - 0, 0); // no-op placeholder removed below
    }
    // (clean wait logic)
    if (L == 2) {
      poll_n(p.flags + (size_t)(FLPA + t * GPA) * FPAD - (size_t)(FLPA + t * GPA) * FPAD + (size_t)(FLPA + t * GPA) * FPAD, 0);
    }
    // NOTE: the above two lines are inert (n=0); real waits follow:
    if (L == 2) {
      { int* fb = p.flags + (size_t)(FLPA + t * GPA) * FPAD; poll_n(fb, GPA); }
      if (t > 0) { int* fb = p.flags + (size_t)(FL2 + (t - 1) * G2) * FPAD; poll_n(fb, G2); }
    } else if (L == 3) {
      { int* fb = p.flags + (size_t)(FL2 + t * G2) * FPAD; poll_n(fb, G2); }
      if (t > 0) { int* fb = p.flags + (size_t)(FL3 + (t - 1) * G3) * FPAD; poll_n(fb, G3); }
    }
    __syncthreads();
    acq();

    const float* hprev = (t == 0) ? (p.h0 + (size_t)(L - 1) * B_ * H_)
                                  : (hs + (size_t)((t - 1) & 1) * B_ * H_);

    float acc[4][2];
#pragma unroll
    for (int r = 0; r < 4; ++r) { acc[r][0] = 0.f; acc[r][1] = 0.f; }

    for (int ci = 0; ci < NCH; ++ci) {
      // stage 64x80 activation chunk into LDS
      for (int idx = tid; idx < 64 * 80; idx += 256) {
        const int b = idx / 80;
        const int fl = idx - b * 80;
        float v;
        if (ci < INCH) {
          const int f = ci * 80 + fl;
          if (L == 1) {
            if (f < 3) v = p.x[((size_t)b * T_ + t) * 3 + f];
            else v = (t == 0) ? p.pwv[(size_t)b * V_ + (f - 3)]
                              : p.out_wv[((size_t)b * T_ + (t - 1)) * V_ + (f - 3)];
          } else {
            if (f < 3) v = p.x[((size_t)b * T_ + t) * 3 + f];
            else if (f < 403) v = __bfloat162float(hin[((size_t)t * B_ + b) * H_ + (f - 3)]);
            else v = p.out_wv[((size_t)b * T_ + t) * V_ + (f - 403)];
          }
        } else {
          const int f = (ci - INCH) * 80 + fl;
          v = hprev[(size_t)b * H_ + f];
        }
        smem[b * 84 + fl] = v;
      }
      __syncthreads();

      if (cb < NCOL) {
        const int lc0 = cb, lc1 = cb + 1;
        const int gc0 = (lc0 & 3) * H_ + u0 + (lc0 >> 2);
        const int gc1 = (lc1 & 3) * H_ + u0 + (lc1 >> 2);
        const float* w0 = (ci < INCH) ? (wih + (size_t)gc0 * INW + ci * 80)
                                      : (whh + (size_t)gc0 * H_ + (ci - INCH) * 80);
        const float* w1 = (ci < INCH) ? (wih + (size_t)gc1 * INW + ci * 80)
                                      : (whh + (size_t)gc1 * H_ + (ci - INCH) * 80);
        const float* a0 = smem + (tb * 4 + 0) * 84;
        const float* a1 = smem + (tb * 4 + 1) * 84;
        const float* a2 = smem + (tb * 4 + 2) * 84;
        const float* a3 = smem + (tb * 4 + 3) * 84;
#pragma unroll
        for (int k = 0; k < 80; k += 4) {
          const float4 wa = *(const float4*)(w0 + k);
          const float4 wb = *(const float4*)(w1 + k);
          const float4 x0 = *(const float4*)(a0 + k);
          const float4 x1 = *(const float4*)(a1 + k);
          const float4 x2 = *(const float4*)(a2 + k);
          const float4 x3 = *(const float4*)(a3 + k);
          acc[0][0] += x0.x * wa.x + x0.y * wa.y + x0.z * wa.z + x0.w * wa.w;
          acc[1][0] += x1.x * wa.x + x1.y * wa.y + x1.z * wa.z + x1.w * wa.w;
          acc[2][0] += x2.x * wa.x + x2.y * wa.y + x2.z * wa.z + x2.w * wa.w;
          acc[3][0] += x3.x * wa.x + x3.y * wa.y + x3.z * wa.z + x3.w * wa.w;
          acc[0][1] += x0.x * wb.x + x0.y * wb.y + x0.z * wb.z + x0.w * wb.w;
          acc[1][1] += x1.x * wb.x + x1.y * wb.y + x1.z * wb.z + x1.w * wb.w;
          acc[2][1] += x2.x * wb.x + x2.y * wb.y + x2.z * wb.z + x2.w * wb.w;
          acc[3][1] += x3.x * wb.x + x3.y * wb.y + x3.z * wb.z + x3.w * wb.w;
        }
      }
      __syncthreads();
    }

    // gates -> LDS (+biases)
    if (cb < NCOL) {
      const int lc0 = cb, lc1 = cb + 1;
      const int gc0 = (lc0 & 3) * H_ + u0 + (lc0 >> 2);
      const int gc1 = (lc1 & 3) * H_ + u0 + (lc1 >> 2);
      const float bia0 = bih[gc0] + bhh[gc0];
      const float bia1 = bih[gc1] + bhh[gc1];
#pragma unroll
      for (int r = 0; r < 4; ++r) {
        const int b = tb * 4 + r;
        gsm[b * (NCOL + 1) + lc0] = acc[r][0] + bia0;
        gsm[b * (NCOL + 1) + lc1] = acc[r][1] + bia1;
      }
    }
    __syncthreads();

    // cell update for owned hidden units
    const float* cprev = (t == 0) ? (p.c0 + (size_t)(L - 1) * B_ * H_) : cs;
    for (int idx = tid; idx < 64 * NU; idx += 256) {
      const int b = idx / NU;
      const int ul = idx - b * NU;
      const int u = u0 + ul;
      const float gi = gsm[b * (NCOL + 1) + ul * 4 + 0];
      const float gf = gsm[b * (NCOL + 1) + ul * 4 + 1];
      const float gg = gsm[b * (NCOL + 1) + ul * 4 + 2];
      const float go = gsm[b * (NCOL + 1) + ul * 4 + 3];
      const float cn = sigm(gf) * cprev[(size_t)b * H_ + u] + sigm(gi) * tanhf(gg);
      const float hn = sigm(go) * tanhf(cn);
      cs[(size_t)b * H_ + u] = cn;
      hs[(size_t)(t & 1) * B_ * H_ + (size_t)b * H_ + u] = hn;
      hout[((size_t)t * B_ + b) * H_ + u] = __float2bfloat16(hn);
    }

    rel();
    __syncthreads();
    if (tid == 0) {
      const int base = (L == 1) ? FL1 : (L == 2) ? FL2 : FL3;
      const int g = (L == 1) ? G1 : (L == 2) ? G2 : G3;
      atomicAdd(p.flags + (size_t)(base + t * g + wg) * FPAD, 1);
    }
  }
}

// ---------------- attention group ----------------
__device__ void pa_role(const P& p, int pa, float* smem) {
  const int tid = threadIdx.x;
  const int b0 = pa * 8;
  float* kst = p.ws + KST;
  float* hsm = smem;            // 8*400
  float* mixs = smem + 3200;    // 240
  float* kaps = smem + 3440;    // 80
  float* phis = smem + 3520;    // 400
  float* wvs = smem + 3920;     // 616
  float* hs1 = p.ws + HS1;
  for (int t = 0; t < T_; ++t) {
    { int* fb = p.flags + (size_t)(FL1 + t * G1) * FPAD; poll_n(fb, G1); }
    __syncthreads();
    acq();
    for (int bl = 0; bl < 8; ++bl)
      for (int r = tid; r < H_; r += 256)
        hsm[bl * H_ + r] = hs1[(size_t)(t & 1) * B_ * H_ + (size_t)(b0 + bl) * H_ + r];
    __syncthreads();
    if (tid < 240) {
      const int bl = tid / 30, m = tid - (tid / 30) * 30;
      const float* hr = hsm + bl * H_;
      const float* wr = p.wwin + (size_t)m * H_;
      float d = 0.f;
#pragma unroll 4
      for (int k = 0; k < H_; ++k) d += hr[k] * wr[k];
      mixs[tid] = __expf(d + p.bwin[m]);
    }
    __syncthreads();
    if (tid < 80) {
      const int bl = tid / 10, k = tid - (tid / 10) * 10;
      const int b = b0 + bl;
      const float prev = (t == 0) ? p.pkap[b * K_ + k] : kst[b * K_ + k];
      const float kap = prev + mixs[bl * 30 + 20 + k];
      kst[b * K_ + k] = kap;
      kaps[bl * 10 + k] = kap;
      if (t == T_ - 1) p.out_kap[b * K_ + k] = kap;
    }
    __syncthreads();
    for (int i = tid; i < 8 * 50; i += 256) {
      const int bl = i / 50, u = i - (i / 50) * 50;
      const int b = b0 + bl;
      float s = 0.f;
      const float uu = (float)u;
#pragma unroll
      for (int k = 0; k < 10; ++k) {
        const float df = kaps[bl * 10 + k] - uu;
        s += mixs[bl * 30 + k] * __expf(-mixs[bl * 30 + 10 + k] * df * df);
      }
      phis[i] = s * p.tmask[b * U_ + u];
    }
    __syncthreads();
    for (int i = tid; i < 8 * 77; i += 256) wvs[i] = 0.f;
    __syncthreads();
    if (tid < 8) {
      const int b = b0 + tid;
      for (int u = 0; u < U_; ++u) wvs[tid * 77 + p.text[b * U_ + u]] += phis[tid * 50 + u];
    }
    __syncthreads();
    for (int i = tid; i < 8 * 77; i += 256) {
      const int bl = i / 77, v = i - (i / 77) * 77;
      p.out_wv[((size_t)(b0 + bl) * T_ + t) * V_ + v] = wvs[i];
    }
    rel();
    __syncthreads();
    if (tid == 0) atomicAdd(p.flags + (size_t)(FLPA + t * GPA + pa) * FPAD, 1);
  }
}

// ---------------- output projection group ----------------
__device__ void out_role(const P& p, int g, float* smem) {
  const int tid = threadIdx.x;
  const int c0g = (g < 9) ? g * 8 : 72 + (g - 9) * 7;
  const int nc = (g < 9) ? 8 : 7;
  const int tc = tid & 7, tb = tid >> 3;  // tb in [0,32)
  for (int t = 0; t < T_; ++t) {
    { int* fb = p.flags + (size_t)(FL3 + t * G3) * FPAD; poll_n(fb, G3); }
    __syncthreads();
    acq();
    float a0 = 0.f, a1 = 0.f;
    for (int ci = 0; ci < 15; ++ci) {
      for (int idx = tid; idx < 64 * 80; idx += 256) {
        const int b = idx / 80;
        const int fl = idx - b * 80;
        const int f = ci * 80 + fl;
        float v;
        if (f < 400) v = __bfloat162float(p.hid1[((size_t)t * B_ + b) * H_ + f]);
        else if (f < 800) v = __bfloat162float(p.hid2[((size_t)t * B_ + b) * H_ + (f - 400)]);
        else v = __bfloat162float(p.hid3[((size_t)t * B_ + b) * H_ + (f - 800)]);
        smem[b * 84 + fl] = v;
      }
      __syncthreads();
      if (tc < nc) {
        const float* wr = p.wout + (size_t)(c0g + tc) * 1200 + ci * 80;
        const float* r0 = smem + (tb * 2 + 0) * 84;
        const float* r1 = smem + (tb * 2 + 1) * 84;
#pragma unroll
        for (int k = 0; k < 80; k += 4) {
          const float4 w4 = *(const float4*)(wr + k);
          const float4 xa = *(const float4*)(r0 + k);
          const float4 xb = *(const float4*)(r1 + k);
          a0 += xa.x * w4.x + xa.y * w4.y + xa.z * w4.z + xa.w * w4.w;
          a1 += xb.x * w4.x + xb.y * w4.y + xb.z * w4.z + xb.w * w4.w;
        }
      }
      __syncthreads();
    }
    if (tc < nc) {
      const int c = c0g + tc;
      const float bv = p.bout[c];
      p.out_y[((size_t)(tb * 2 + 0) * T_ + t) * OUT_ + c] = a0 + bv;
      p.out_y[((size_t)(tb * 2 + 1) * T_ + t) * OUT_ + c] = a1 + bv;
    }
  }
}

__global__ __launch_bounds__(256) void hw_pipeline(P p) {
  __shared__ float smem_[7488];
  const int bid = blockIdx.x;
  if (bid < G1) lstm_role<1>(p, bid, smem_);
  else if (bid < G1 + GPA) pa_role(p, bid - G1, smem_);
  else if (bid < G1 + GPA + G2) lstm_role<2>(p, bid - G1 - GPA, smem_);
  else if (bid < G1 + GPA + G2 + G3) lstm_role<3>(p, bid - G1 - GPA - G2, smem_);
  else out_role(p, bid - G1 - GPA - G2 - G3, smem_);
}

extern "C" void kernel_launch(void* const* d_in, const int* in_sizes, int n_in,
                              void* d_out, int out_size, void* d_ws, size_t ws_size,
                              hipStream_t stream) {
  (void)in_sizes; (void)n_in; (void)out_size; (void)ws_size;
  P p;
  p.x = (const float*)d_in[0];
  p.text = (const int*)d_in[1];
  p.tmask = (const float*)d_in[2];
  p.h0 = (const float*)d_in[3];
  p.c0 = (const float*)d_in[4];
  p.pwv = (const float*)d_in[5];
  p.pkap = (const float*)d_in[6];
  p.wih1 = (const float*)d_in[7];  p.whh1 = (const float*)d_in[8];
  p.bih1 = (const float*)d_in[9];  p.bhh1 = (const float*)d_in[10];
  p.wih2 = (const float*)d_in[11]; p.whh2 = (const float*)d_in[12];
  p.bih2 = (const float*)d_in[13]; p.bhh2 = (const float*)d_in[14];
  p.wih3 = (const float*)d_in[15]; p.whh3 = (const float*)d_in[16];
  p.bih3 = (const float*)d_in[17]; p.bhh3 = (const float*)d_in[18];
  p.wwin = (const float*)d_in[19]; p.bwin = (const float*)d_in[20];
  p.wout = (const float*)d_in[21]; p.bout = (const float*)d_in[22];
  float* out = (float*)d_out;
  p.out_y = out;
  p.out_wv = out + (size_t)B_ * T_ * OUT_;
  p.out_kap = p.out_wv + (size_t)B_ * T_ * V_;
  p.ws = (float*)d_ws;
  p.hid1 = (__hip_bfloat16*)((char*)d_ws + HID1_B);
  p.hid2 = (__hip_bfloat16*)((char*)d_ws + HID2_B);
  p.hid3 = (__hip_bfloat16*)((char*)d_ws + HID3_B);
  p.flags = (int*)((char*)d_ws + FLAG_B);
  hipMemsetAsync((char*)d_ws + FLAG_B, 0, (size_t)NFLAGS * FPAD * sizeof(int), stream);
  hipLaunchKernelGGL(hw_pipeline, dim3(NBLK), dim3(256), 0, stream, p);
}

// Round 2
// 62966.357 us; speedup vs baseline: 1.3653x; 1.3653x over previous
//
#include <hip/hip_runtime.h>
#include <hip/hip_bf16.h>
#include <cstdint>
#include <cstddef>
#include <cstring>

using u32 = unsigned int;
using u64 = unsigned long long;

constexpr int B_=64, T_=600, U_=50, H_=400, V_=77, K_=10, OUT_=121;
constexpr int G1=50, GPA=8, G2=50, G3=50, GOUT=16;
constexpr int NBLK = G1+GPA+G2+G3+GOUT; // 174

// ---- ws byte offsets ----
constexpr size_t FLAGS_B = 0;
constexpr size_t FLAGS_SZ = 5ull*600*16*4;           // 192000
constexpr size_t HS1_B = 192256;
constexpr size_t HSSZ  = 2ull*B_*H_*4;               // 204800 (ping-pong h)
constexpr size_t HS2_B = HS1_B + HSSZ;
constexpr size_t HS3_B = HS2_B + HSSZ;
constexpr size_t W1_B  = HS3_B + HSSZ;               // repacked [wih1|whh1] 1600x480
constexpr size_t W2_B  = W1_B + 1600ull*480*4;       // repacked [x,wv,h1|whh2] 1600x880
constexpr size_t W3_B  = W2_B + 1600ull*880*4;
constexpr size_t HID1_B = W3_B + 1600ull*880*4;      // bf16 [T][B][H]
constexpr size_t HIDSZ_B = (size_t)T_*B_*H_*2;       // 30,720,000
constexpr size_t HID2_B = HID1_B + HIDSZ_B;
constexpr size_t HID3R_B = HID2_B + HIDSZ_B;         // ring [64][B][H] bf16
// total ~79.4 MB

struct P {
  const float *x, *tmask, *h0, *c0, *pwv, *pkap;
  const int *text;
  const float *wih1,*whh1,*bih1,*bhh1;
  const float *wih2,*whh2,*bih2,*bhh2;
  const float *wih3,*whh3,*bih3,*bhh3;
  const float *wwin,*bwin,*wout,*bout;
  float *out_y,*out_wv,*out_kap;
  float *hs1,*hs2,*hs3,*w1,*w2,*w3;
  u32 *hid1,*hid2,*hid3r;
  int *flags;
};

// ---- coherent (agent-scope, L2-bypassing) access helpers ----
__device__ __forceinline__ float ldc_f(const float* p) {
  return __hip_atomic_load((float*)p, __ATOMIC_RELAXED, __HIP_MEMORY_SCOPE_AGENT);
}
__device__ __forceinline__ void stc_f(float* p, float v) {
  __hip_atomic_store(p, v, __ATOMIC_RELAXED, __HIP_MEMORY_SCOPE_AGENT);
}
__device__ __forceinline__ u32 ldc_u(const u32* p) {
  return __hip_atomic_load((u32*)p, __ATOMIC_RELAXED, __HIP_MEMORY_SCOPE_AGENT);
}
__device__ __forceinline__ void stc_u(u32* p, u32 v) {
  __hip_atomic_store(p, v, __ATOMIC_RELAXED, __HIP_MEMORY_SCOPE_AGENT);
}
__device__ __forceinline__ float2 ldc_f2(const float* p) {
  u64 x = __hip_atomic_load((u64*)p, __ATOMIC_RELAXED, __HIP_MEMORY_SCOPE_AGENT);
  float2 r; memcpy(&r, &x, 8); return r;
}
__device__ __forceinline__ float2 unpack_bf16(u32 pv) {
  u32 a = pv << 16, b = pv & 0xffff0000u;
  float2 r; memcpy(&r.x, &a, 4); memcpy(&r.y, &b, 4); return r;
}
__device__ __forceinline__ u32 pack_bf16(float a, float b) {
  __hip_bfloat162 h2; h2.x = __float2bfloat16(a); h2.y = __float2bfloat16(b);
  u32 r; memcpy(&r, &h2, 4); return r;
}
__device__ __forceinline__ float sigm(float x) { return 1.f/(1.f+__expf(-x)); }

// stages: 0=F1 1=FPA 2=F2 3=F3 4=FO ; one counter (64B-padded) per (stage,t)
__device__ __forceinline__ void poll1(int* flags, int stage, int t, int target) {
  if (threadIdx.x == 0) {
    int* f = flags + ((size_t)stage*600 + t)*16;
    while (__hip_atomic_load(f, __ATOMIC_RELAXED, __HIP_MEMORY_SCOPE_AGENT) < target)
      __builtin_amdgcn_s_sleep(4);
  }
}
__device__ __forceinline__ void set_flag(int* flags, int stage, int t) {
  // caller guarantees a __syncthreads() (vmcnt-draining) precedes this
  if (threadIdx.x == 0)
    __hip_atomic_fetch_add(flags + ((size_t)stage*600 + t)*16, 1,
                           __ATOMIC_RELAXED, __HIP_MEMORY_SCOPE_AGENT);
}

// ================= LSTM stage (L = 1,2,3), 50 wgs of 8 units each =============
template <int L>
__device__ void lstm_role(const P& p, int wg, float* smem) {
  const int tid = threadIdx.x;
  constexpr int KW   = (L==1) ? 480 : 880;
  constexpr int NCH  = KW/80;
  constexpr int INCH = (L==1) ? 1 : 6;
  const int cg = tid & 7, bg = tid >> 3;
  const int u  = wg*8 + cg;        // hidden unit owned by this thread
  const int b0 = bg*2;             // 2 batches per thread
  float* repW = (L==1) ? p.w1 : (L==2) ? p.w2 : p.w3;
  const float* wih = (L==1) ? p.wih1 : (L==2) ? p.wih2 : p.wih3;
  const float* whh = (L==1) ? p.whh1 : (L==2) ? p.whh2 : p.whh3;
  const float* bih = (L==1) ? p.bih1 : (L==2) ? p.bih2 : p.bih3;
  const float* bhh = (L==1) ? p.bhh1 : (L==2) ? p.bhh2 : p.bhh3;
  float* hsL = (L==1) ? p.hs1 : (L==2) ? p.hs2 : p.hs3;
  const u32* hin = (L==2) ? p.hid1 : p.hid2;  // L1: unused
  u32* hout = (L==1) ? p.hid1 : (L==2) ? p.hid2 : p.hid3r;
  constexpr int STG = (L==1) ? 0 : (L==2) ? 2 : 3;

  // ---- one-time weight repack: row-contiguous [reordered wih | whh], K=KW ----
  for (int e = tid; e < 32*KW; e += 256) {
    int lr = e / KW, j = e - lr*KW;
    int g = lr >> 3, cu = lr & 7;
    int r = g*400 + wg*8 + cu;
    float v;
    if (L == 1) v = (j < 80) ? wih[(size_t)r*80 + j] : whh[(size_t)r*400 + (j-80)];
    else {
      if (j < 3)        v = wih[(size_t)r*480 + j];
      else if (j < 80)  v = wih[(size_t)r*480 + 403 + (j-3)];
      else if (j < 480) v = wih[(size_t)r*480 + 3 + (j-80)];
      else              v = whh[(size_t)r*400 + (j-480)];
    }
    repW[(size_t)r*KW + j] = v;
  }
  float bsum[4];
  const float* wr[4];
#pragma unroll
  for (int g = 0; g < 4; ++g) {
    bsum[g] = bih[g*400+u] + bhh[g*400+u];
    wr[g] = repW + (size_t)(g*400+u)*KW;
  }
  float creg[2];
  creg[0] = p.c0[(size_t)(L-1)*B_*H_ + (size_t)b0*H_ + u];
  creg[1] = p.c0[(size_t)(L-1)*B_*H_ + (size_t)(b0+1)*H_ + u];

  for (int t = 0; t < T_; ++t) {
    const int par = t & 1;
    if (L == 1)      { if (t > 0) poll1(p.flags, 1, t-1, GPA); }
    else if (L == 2) { poll1(p.flags, 1, t, GPA); if (t > 0) poll1(p.flags, 2, t-1, G2); }
    else             { poll1(p.flags, 2, t, G2);  if (t > 0) poll1(p.flags, 3, t-1, G3);
                       if (t >= 64) poll1(p.flags, 4, t-64, 1); }
    __syncthreads();

    const float* hprev = (t == 0) ? (p.h0 + (size_t)(L-1)*B_*H_)
                                  : (hsL + (size_t)(par^1)*B_*H_);
    float acc[2][4] = {{0.f,0.f,0.f,0.f},{0.f,0.f,0.f,0.f}};

    for (int ci = 0; ci < NCH; ++ci) {
      if (ci == 0) {                       // features [x(3) | wv(77)]
        for (int idx = tid; idx < 5120; idx += 256) {
          int b = idx / 80, f = idx - b*80;
          float v;
          if (f < 3) v = p.x[((size_t)b*600 + t)*3 + f];
          else if (L == 1 && t == 0) v = p.pwv[(size_t)b*77 + (f-3)];
          else {
            int tt = (L == 1) ? t-1 : t;
            v = ldc_f(p.out_wv + ((size_t)b*600 + tt)*77 + (f-3));
          }
          smem[b*84 + f] = v;
        }
      } else if (ci < INCH) {              // hid_in bf16 pairs (L>=2)
        for (int idx = tid; idx < 2560; idx += 256) {
          int b = idx / 40, fp = idx - b*40;
          u32 pv = ldc_u(hin + ((size_t)t*64 + b)*200 + (ci-1)*40 + fp);
          *(float2*)(smem + b*84 + 2*fp) = unpack_bf16(pv);
        }
      } else {                             // recurrent h chunks
        int hc = ci - INCH;
        for (int idx = tid; idx < 2560; idx += 256) {
          int b = idx / 40, fp = idx - b*40;
          const float* src = hprev + (size_t)b*400 + hc*80 + 2*fp;
          float2 f2 = (t == 0) ? *(const float2*)src : ldc_f2(src);
          *(float2*)(smem + b*84 + 2*fp) = f2;
        }
      }
      __syncthreads();
      {
        const float* a0p = smem + b0*84;
        const float* a1p = a0p + 84;
        const int ko = ci*80;
#pragma unroll
        for (int k = 0; k < 80; k += 4) {
          float4 a0 = *(const float4*)(a0p + k);
          float4 a1 = *(const float4*)(a1p + k);
#pragma unroll
          for (int g = 0; g < 4; ++g) {
            float4 w4 = *(const float4*)(wr[g] + ko + k);
            acc[0][g] += a0.x*w4.x + a0.y*w4.y + a0.z*w4.z + a0.w*w4.w;
            acc[1][g] += a1.x*w4.x + a1.y*w4.y + a1.z*w4.z + a1.w*w4.w;
          }
        }
      }
      __syncthreads();
    }

    // ---- in-register cell update (thread owns gates i,f,g,o of unit u, 2 batches)
    float hn[2];
#pragma unroll
    for (int r = 0; r < 2; ++r) {
      float gi = acc[r][0]+bsum[0], gf = acc[r][1]+bsum[1];
      float gg = acc[r][2]+bsum[2], go = acc[r][3]+bsum[3];
      float cn = sigm(gf)*creg[r] + sigm(gi)*tanhf(gg);
      creg[r] = cn;
      hn[r] = sigm(go)*tanhf(cn);
      stc_f(hsL + (size_t)par*B_*H_ + (size_t)(b0+r)*H_ + u, hn[r]);
    }
    // hid bf16 pair-pack via LDS exchange (reuses chunk buffer)
    smem[b0*8 + cg] = hn[0];
    smem[(b0+1)*8 + cg] = hn[1];
    __syncthreads();
    {
      int b = tid >> 2, j = tid & 3;
      u32 pk = pack_bf16(smem[b*8 + 2*j], smem[b*8 + 2*j + 1]);
      size_t tt = (L == 3) ? (size_t)(t & 63) : (size_t)t;
      stc_u(hout + (tt*64 + b)*200 + wg*4 + j, pk);
    }
    __syncthreads();
    set_flag(p.flags, STG, t);
  }
}

// ================= attention stage, 8 wgs of 8 batches each ===================
__device__ void pa_role(const P& p, int pa, float* smem) {
  const int tid = threadIdx.x;
  const int b0p = pa*8;
  float* hsm  = smem;          // 8*404
  float* mixs = smem + 3232;   // 240
  float* kaps = smem + 3472;   // 80
  float* phis = smem + 3552;   // 400
  float* wvs  = smem + 3952;   // 616
  float kap_reg = 0.f;
  if (tid < 80) kap_reg = p.pkap[(size_t)(b0p + tid/10)*10 + (tid % 10)];

  for (int t = 0; t < T_; ++t) {
    poll1(p.flags, 0, t, G1);
    __syncthreads();
    for (int idx = tid; idx < 1600; idx += 256) {
      int bl = idx / 200, pp = idx - bl*200;
      float2 f2 = ldc_f2(p.hs1 + (size_t)(t&1)*B_*H_ + (size_t)(b0p+bl)*400 + 2*pp);
      *(float2*)(hsm + bl*404 + 2*pp) = f2;
    }
    __syncthreads();
    if (tid < 240) {
      int bl = tid / 30, m = tid - (tid/30)*30;
      const float* hr = hsm + bl*404;
      const float* wrow = p.wwin + (size_t)m*400;
      float d = 0.f;
#pragma unroll 5
      for (int k = 0; k < 400; k += 4) {
        float4 hv = *(const float4*)(hr + k);
        float4 w4 = *(const float4*)(wrow + k);
        d += hv.x*w4.x + hv.y*w4.y + hv.z*w4.z + hv.w*w4.w;
      }
      mixs[bl*30 + m] = __expf(d + p.bwin[m]);
    }
    __syncthreads();
    if (tid < 80) {
      int bl = tid/10, kk = tid - (tid/10)*10;
      kap_reg += mixs[bl*30 + 20 + kk];
      kaps[bl*10 + kk] = kap_reg;
      if (t == T_-1) stc_f(p.out_kap + (size_t)(b0p+bl)*10 + kk, kap_reg);
    }
    __syncthreads();
    for (int i = tid; i < 400; i += 256) {
      int bl = i / 50, uu = i - (i/50)*50;
      float s = 0.f; const float fu = (float)uu;
#pragma unroll
      for (int k = 0; k < 10; ++k) {
        float df = kaps[bl*10+k] - fu;
        s += mixs[bl*30+k] * __expf(-mixs[bl*30+10+k]*df*df);
      }
      phis[i] = s * p.tmask[(size_t)(b0p+bl)*50 + uu];
    }
    for (int i = tid; i < 616; i += 256) wvs[i] = 0.f;
    __syncthreads();
    if (tid < 8) {
      int b = b0p + tid;
      for (int uu = 0; uu < 50; ++uu)
        wvs[tid*77 + p.text[(size_t)b*50 + uu]] += phis[tid*50 + uu];
    }
    __syncthreads();
    for (int i = tid; i < 616; i += 256) {
      int bl = i / 77, v = i - (i/77)*77;
      stc_f(p.out_wv + ((size_t)(b0p+bl)*600 + t)*77 + v, wvs[i]);
    }
    __syncthreads();
    set_flag(p.flags, 1, t);
  }
}

// ================= output projection, 16 wgs, t-interleaved ===================
__device__ void out_role(const P& p, int g, float* smem) {
  const int tid = threadIdx.x;
  const int cg = tid & 31, bg = tid >> 5;
  const int c0 = cg*4;
  const float* wrp[4]; float bo[4];
#pragma unroll
  for (int j = 0; j < 4; ++j) {
    int c = c0 + j; if (c > 120) c = 120;
    wrp[j] = p.wout + (size_t)c*1200;
    bo[j] = p.bout[c];
  }
  for (int t = g; t < T_; t += GOUT) {
    poll1(p.flags, 3, t, G3);
    __syncthreads();
    float acc[8][4];
#pragma unroll
    for (int r = 0; r < 8; ++r)
#pragma unroll
      for (int j = 0; j < 4; ++j) acc[r][j] = 0.f;

    for (int ci = 0; ci < 15; ++ci) {
      for (int idx = tid; idx < 2560; idx += 256) {
        int b = idx / 40, fp = idx - b*40;
        int f = ci*80 + 2*fp;
        u32 pv;
        if (f < 400)      pv = ldc_u(p.hid1 + ((size_t)t*64 + b)*200 + (f>>1));
        else if (f < 800) pv = ldc_u(p.hid2 + ((size_t)t*64 + b)*200 + ((f-400)>>1));
        else              pv = ldc_u(p.hid3r + ((size_t)(t&63)*64 + b)*200 + ((f-800)>>1));
        *(float2*)(smem + b*84 + 2*fp) = unpack_bf16(pv);
      }
      __syncthreads();
#pragma unroll 4
      for (int k = 0; k < 80; k += 4) {
        float4 w4[4];
#pragma unroll
        for (int j = 0; j < 4; ++j) w4[j] = *(const float4*)(wrp[j] + ci*80 + k);
#pragma unroll
        for (int r = 0; r < 8; ++r) {
          float4 a = *(const float4*)(smem + (size_t)(bg*8+r)*84 + k);
#pragma unroll
          for (int j = 0; j < 4; ++j)
            acc[r][j] += a.x*w4[j].x + a.y*w4[j].y + a.z*w4[j].z + a.w*w4[j].w;
        }
      }
      __syncthreads();
    }
#pragma unroll
    for (int r = 0; r < 8; ++r)
#pragma unroll
      for (int j = 0; j < 4; ++j) {
        int c = c0 + j;
        if (c < 121)
          p.out_y[((size_t)(bg*8+r)*600 + t)*121 + c] = acc[r][j] + bo[j];
      }
    __syncthreads();
    set_flag(p.flags, 4, t);
  }
}

__global__ __launch_bounds__(256) void hw_pipeline(P p) {
  __shared__ float smem_[5440];
  const int bid = blockIdx.x;
  if (bid < G1) lstm_role<1>(p, bid, smem_);
  else if (bid < G1+GPA) pa_role(p, bid - G1, smem_);
  else if (bid < G1+GPA+G2) lstm_role<2>(p, bid - G1 - GPA, smem_);
  else if (bid < G1+GPA+G2+G3) lstm_role<3>(p, bid - G1 - GPA - G2, smem_);
  else out_role(p, bid - G1 - GPA - G2 - G3, smem_);
}

extern "C" void kernel_launch(void* const* d_in, const int* in_sizes, int n_in,
                              void* d_out, int out_size, void* d_ws, size_t ws_size,
                              hipStream_t stream) {
  (void)in_sizes; (void)n_in; (void)out_size; (void)ws_size;
  P p;
  p.x = (const float*)d_in[0];
  p.text = (const int*)d_in[1];
  p.tmask = (const float*)d_in[2];
  p.h0 = (const float*)d_in[3];
  p.c0 = (const float*)d_in[4];
  p.pwv = (const float*)d_in[5];
  p.pkap = (const float*)d_in[6];
  p.wih1 = (const float*)d_in[7];  p.whh1 = (const float*)d_in[8];
  p.bih1 = (const float*)d_in[9];  p.bhh1 = (const float*)d_in[10];
  p.wih2 = (const float*)d_in[11]; p.whh2 = (const float*)d_in[12];
  p.bih2 = (const float*)d_in[13]; p.bhh2 = (const float*)d_in[14];
  p.wih3 = (const float*)d_in[15]; p.whh3 = (const float*)d_in[16];
  p.bih3 = (const float*)d_in[17]; p.bhh3 = (const float*)d_in[18];
  p.wwin = (const float*)d_in[19]; p.bwin = (const float*)d_in[20];
  p.wout = (const float*)d_in[21]; p.bout = (const float*)d_in[22];
  float* out = (float*)d_out;
  p.out_y  = out;
  p.out_wv = out + (size_t)B_*T_*OUT_;
  p.out_kap = p.out_wv + (size_t)B_*T_*V_;
  char* ws = (char*)d_ws;
  p.flags = (int*)(ws + FLAGS_B);
  p.hs1 = (float*)(ws + HS1_B);
  p.hs2 = (float*)(ws + HS2_B);
  p.hs3 = (float*)(ws + HS3_B);
  p.w1  = (float*)(ws + W1_B);
  p.w2  = (float*)(ws + W2_B);
  p.w3  = (float*)(ws + W3_B);
  p.hid1 = (u32*)(ws + HID1_B);
  p.hid2 = (u32*)(ws + HID2_B);
  p.hid3r = (u32*)(ws + HID3R_B);
  hipMemsetAsync(ws + FLAGS_B, 0, FLAGS_SZ, stream);
  hipLaunchKernelGGL(hw_pipeline, dim3(NBLK), dim3(256), 0, stream, p);
}

// Round 5
// 26975.562 us; speedup vs baseline: 3.1868x; 2.3342x over previous
//
#include <hip/hip_runtime.h>
#include <hip/hip_bf16.h>
#include <cstdint>
#include <cstddef>
#include <cstring>

using u32 = unsigned int;
using u64 = unsigned long long;
typedef _Float16 h2 __attribute__((ext_vector_type(2)));
typedef _Float16 h4 __attribute__((ext_vector_type(4)));

constexpr int B_=64, T_=600, U_=50, H_=400, V_=77, K_=10, OUT_=121;
constexpr int G1=50, GPA=8, G2=50, G3=50, GOUT=8;
constexpr int NBLK = G1+GPA+G2+G3+GOUT; // 166

// flag targets
constexpr int TF0=G1, TF1=GPA, TF2=G2, TF3=G3;

// ---- ws byte offsets ----
constexpr size_t FLAGS_B = 0;                       // 5*600 counters, 128B stride
constexpr size_t FLAGS_SZ = 5ull*600*32*4;          // 384000
constexpr size_t HS1_B = 384000;                    // [2][64][400] fp32 ping-pong
constexpr size_t HSSZ  = 2ull*B_*H_*4;              // 204800
constexpr size_t HS2_B = HS1_B + HSSZ;
constexpr size_t HS3_B = HS2_B + HSSZ;
constexpr size_t W1F_B = HS3_B + HSSZ;              // f16 [1600][480]
constexpr size_t W2F_B = W1F_B + 1600ull*480*2;
constexpr size_t W3F_B = W2F_B + 1600ull*880*2;
constexpr size_t WOF_B = W3F_B + 1600ull*880*2;     // f16 [8(per-wg copy)][121][1200]
constexpr size_t WOFCOPY = 121ull*1200;             // elements per copy
constexpr size_t FF2_B = WOF_B + 8ull*WOFCOPY*2 + 96; // u32 [600][64][240] f16-pairs
constexpr size_t FFSZ  = 600ull*64*240*4;
constexpr size_t FF3_B = FF2_B + FFSZ;
constexpr size_t H3R_B = FF3_B + FFSZ;              // u32 [64][64][200] ring
// total ~88 MB

// LDS layout (bytes inside smem_raw)
constexpr int SW2 = 228;   // f16 stride, L2/L3 phase panel (220 dims)
constexpr int SW1 = 164;   // L1 (160 dims)
constexpr int SWO = 244;   // OUT (240 dims)
constexpr int EXOFF = 58368;  // fp32 exchange 64x8
constexpr int SMEM_BYTES = 60416;

struct P {
  const float *x, *tmask, *h0, *c0, *pwv, *pkap;
  const int *text;
  const float *wih1,*whh1,*bih1,*bhh1;
  const float *wih2,*whh2,*bih2,*bhh2;
  const float *wih3,*whh3,*bih3,*bhh3;
  const float *wwin,*bwin,*wout,*bout;
  float *out_y,*out_wv,*out_kap;
  float *hs1,*hs2,*hs3;
  _Float16 *w1f,*w2f,*w3f,*wof;
  u32 *ff2,*ff3,*h3r;
  int *flags;
};

// ---- coherent (agent-scope) helpers ----
__device__ __forceinline__ float ldc_f(const float* p) {
  return __hip_atomic_load((float*)p, __ATOMIC_RELAXED, __HIP_MEMORY_SCOPE_AGENT);
}
__device__ __forceinline__ void stc_f(float* p, float v) {
  __hip_atomic_store(p, v, __ATOMIC_RELAXED, __HIP_MEMORY_SCOPE_AGENT);
}
__device__ __forceinline__ u32 ldc_u(const u32* p) {
  return __hip_atomic_load((u32*)p, __ATOMIC_RELAXED, __HIP_MEMORY_SCOPE_AGENT);
}
__device__ __forceinline__ void stc_u(u32* p, u32 v) {
  __hip_atomic_store(p, v, __ATOMIC_RELAXED, __HIP_MEMORY_SCOPE_AGENT);
}
__device__ __forceinline__ float2 ldc_f2(const float* p) {
  u64 x = __hip_atomic_load((u64*)p, __ATOMIC_RELAXED, __HIP_MEMORY_SCOPE_AGENT);
  float2 r; memcpy(&r, &x, 8); return r;
}
__device__ __forceinline__ float sigm(float x) { return 1.f/(1.f+__expf(-x)); }
__device__ __forceinline__ h2 pk16(float a, float b) {
  auto t = __builtin_amdgcn_cvt_pkrtz(a, b);   // __fp16 ext_vector(2)
  h2 r; memcpy(&r, &t, 4); return r;
}
__device__ __forceinline__ u32 h2u(h2 v) { u32 r; memcpy(&r, &v, 4); return r; }
__device__ __forceinline__ void stpk(u32* dst, h2 v) { stc_u(dst, h2u(v)); }
__device__ __forceinline__ float dot2(h2 a, h2 b, float c) { return __builtin_amdgcn_fdot2(a, b, c, false); }
__device__ __forceinline__ h2 lo4(h4 v) { return __builtin_shufflevector(v, v, 0, 1); }
__device__ __forceinline__ h2 hi4(h4 v) { return __builtin_shufflevector(v, v, 2, 3); }

__device__ __forceinline__ void poll1(int* flags, int stage, int t, int target) {
  if (threadIdx.x == 0) {
    int* f = flags + ((size_t)stage*600 + t)*32;
    while (__hip_atomic_load(f, __ATOMIC_RELAXED, __HIP_MEMORY_SCOPE_AGENT) < target) {}
  }
}
__device__ __forceinline__ void set_flag(int* flags, int stage, int t) {
  // caller guarantees __syncthreads() (vmcnt drained) precedes this
  if (threadIdx.x == 0)
    __hip_atomic_fetch_add(flags + ((size_t)stage*600 + t)*32, 1,
                           __ATOMIC_RELAXED, __HIP_MEMORY_SCOPE_AGENT);
}

// gemm phase: thread owns unit u (4 gate rows), 2 batch rows b0,b0+1
template<int KW, int PH, int SW>
__device__ __forceinline__ void gemm_phase(const _Float16* pan, const _Float16* wf,
                                           int u, int kbase, int b0, float acc[2][4]) {
  const _Float16* a0 = pan + b0*SW;
  const _Float16* a1 = a0 + SW;
  const _Float16* w0 = wf + (size_t)u*KW + kbase;
  const _Float16* w1 = wf + (size_t)(400+u)*KW + kbase;
  const _Float16* w2 = wf + (size_t)(800+u)*KW + kbase;
  const _Float16* w3 = wf + (size_t)(1200+u)*KW + kbase;
#pragma unroll 5
  for (int k = 0; k < PH; k += 4) {
    h4 x0 = *(const h4*)(a0+k), x1 = *(const h4*)(a1+k);
    h4 wa = *(const h4*)(w0+k), wb = *(const h4*)(w1+k);
    h4 wc = *(const h4*)(w2+k), wd = *(const h4*)(w3+k);
    h2 x0l=lo4(x0), x0h=hi4(x0), x1l=lo4(x1), x1h=hi4(x1);
    acc[0][0]=dot2(x0l,lo4(wa),acc[0][0]); acc[0][0]=dot2(x0h,hi4(wa),acc[0][0]);
    acc[0][1]=dot2(x0l,lo4(wb),acc[0][1]); acc[0][1]=dot2(x0h,hi4(wb),acc[0][1]);
    acc[0][2]=dot2(x0l,lo4(wc),acc[0][2]); acc[0][2]=dot2(x0h,hi4(wc),acc[0][2]);
    acc[0][3]=dot2(x0l,lo4(wd),acc[0][3]); acc[0][3]=dot2(x0h,hi4(wd),acc[0][3]);
    acc[1][0]=dot2(x1l,lo4(wa),acc[1][0]); acc[1][0]=dot2(x1h,hi4(wa),acc[1][0]);
    acc[1][1]=dot2(x1l,lo4(wb),acc[1][1]); acc[1][1]=dot2(x1h,hi4(wb),acc[1][1]);
    acc[1][2]=dot2(x1l,lo4(wc),acc[1][2]); acc[1][2]=dot2(x1h,hi4(wc),acc[1][2]);
    acc[1][3]=dot2(x1l,lo4(wd),acc[1][3]); acc[1][3]=dot2(x1h,hi4(wd),acc[1][3]);
  }
}

// ================= LSTM stage template =================
template <int L>
__device__ void lstm_role(const P& p, int wg, char* smem_raw) {
  const int tid = threadIdx.x;
  constexpr int KW = (L==1) ? 480 : 880;
  constexpr int PH = (L==1) ? 160 : 220;
  constexpr int SW = (L==1) ? SW1 : SW2;
  constexpr int STG = (L==1) ? 0 : (L==2) ? 2 : 3;
  const int cg = tid & 7, tb = tid >> 3;
  const int u  = wg*8 + cg;
  const int b0 = tb*2;
  _Float16* wf = (L==1) ? p.w1f : (L==2) ? p.w2f : p.w3f;
  const float* wih = (L==1) ? p.wih1 : (L==2) ? p.wih2 : p.wih3;
  const float* whh = (L==1) ? p.whh1 : (L==2) ? p.whh2 : p.whh3;
  const float* bih = (L==1) ? p.bih1 : (L==2) ? p.bih2 : p.bih3;
  const float* bhh = (L==1) ? p.bhh1 : (L==2) ? p.bhh2 : p.bhh3;
  float* hsL = (L==1) ? p.hs1 : (L==2) ? p.hs2 : p.hs3;
  const u32* ffin = (L==3) ? p.ff3 : p.ff2;   // L2 reads ff2; L3 reads ff3; L1 unused
  _Float16* panA = (_Float16*)smem_raw;
  _Float16* panB = panA + 64*SW;
  float* ex = (float*)(smem_raw + EXOFF);

  // ---- one-time f16 weight repack (own rows only; same-wg write->read) ----
  for (int e = tid; e < 32*KW; e += 256) {
    int lr = e / KW, j = e - lr*KW;
    int g = lr >> 3, cu = lr & 7;
    int r = g*400 + wg*8 + cu;
    float v;
    if (L == 1) {
      if (j < 400)      v = whh[(size_t)r*400 + j];
      else if (j < 477) v = wih[(size_t)r*80 + 3 + (j-400)];
      else              v = wih[(size_t)r*80 + (j-477)];
    } else {
      if (j < 77)       v = wih[(size_t)r*480 + 403 + j];
      else if (j < 80)  v = wih[(size_t)r*480 + (j-77)];
      else if (j < 480) v = wih[(size_t)r*480 + 3 + (j-80)];
      else              v = whh[(size_t)r*400 + (j-480)];
    }
    wf[(size_t)r*KW + j] = (_Float16)v;
  }
  float bsum[4];
#pragma unroll
  for (int g = 0; g < 4; ++g) bsum[g] = bih[g*400+u] + bhh[g*400+u];
  float creg[2];
  creg[0] = p.c0[(size_t)(L-1)*B_*H_ + (size_t)b0*H_ + u];
  creg[1] = p.c0[(size_t)(L-1)*B_*H_ + (size_t)(b0+1)*H_ + u];
  __syncthreads();

  for (int t = 0; t < T_; ++t) {
    const int par = t & 1;
    const float* hsrc = (t == 0) ? (p.h0 + (size_t)(L-1)*B_*H_)
                                 : (hsL + (size_t)(par^1)*B_*H_);
    float acc[2][4] = {{0,0,0,0},{0,0,0,0}};

    if (L == 1) {
      // K-order: [h1rec(400) | wv(77) x(3)]. ph0,ph1 rec; ph2 rec-tail + ff.
      if (t > 0) poll1(p.flags, 0, t-1, TF0);
      __syncthreads();
      // stage ph0 (rec pairs 0..79)
      {
        float2 tmp[20];
#pragma unroll
        for (int it = 0; it < 20; ++it) {
          int idx = tid + it*256; int b = idx/80, pl = idx - b*80;
          tmp[it] = ldc_f2(hsrc + (size_t)b*400 + 2*pl);
        }
#pragma unroll
        for (int it = 0; it < 20; ++it) {
          int idx = tid + it*256; int b = idx/80, pl = idx - b*80;
          *(u32*)(panA + b*SW + 2*pl) = h2u(pk16(tmp[it].x, tmp[it].y));
        }
      }
      __syncthreads();
      // stage ph1 (rec pairs 80..159) || compute ph0
      {
        float2 tmp[20];
#pragma unroll
        for (int it = 0; it < 20; ++it) {
          int idx = tid + it*256; int b = idx/80, pl = idx - b*80;
          tmp[it] = ldc_f2(hsrc + (size_t)b*400 + 160 + 2*pl);
        }
        gemm_phase<KW,PH,SW>(panA, wf, u, 0, b0, acc);
#pragma unroll
        for (int it = 0; it < 20; ++it) {
          int idx = tid + it*256; int b = idx/80, pl = idx - b*80;
          *(u32*)(panB + b*SW + 2*pl) = h2u(pk16(tmp[it].x, tmp[it].y));
        }
      }
      if (t > 0) poll1(p.flags, 1, t-1, TF1);  // PA(t-1) -> wv ready
      __syncthreads();
      // stage ph2 (rec pairs 160..199 + ff scalar 80) || compute ph1
      {
        float2 tmp[10];
#pragma unroll
        for (int it = 0; it < 10; ++it) {
          int idx = tid + it*256; int b = idx/40, pl = idx - b*40;
          tmp[it] = ldc_f2(hsrc + (size_t)b*400 + 320 + 2*pl);
        }
        float tf[20];
#pragma unroll
        for (int it = 0; it < 20; ++it) {
          int idx = tid + it*256; int b = idx/80, j = idx - b*80;
          float v;
          if (j < 77) v = (t == 0) ? p.pwv[(size_t)b*77 + j]
                                   : ldc_f(p.out_wv + ((size_t)b*600 + (t-1))*77 + j);
          else v = p.x[((size_t)b*600 + t)*3 + (j-77)];
          tf[it] = v;
        }
        gemm_phase<KW,PH,SW>(panB, wf, u, 160, b0, acc);
#pragma unroll
        for (int it = 0; it < 10; ++it) {
          int idx = tid + it*256; int b = idx/40, pl = idx - b*40;
          *(u32*)(panA + b*SW + 2*pl) = h2u(pk16(tmp[it].x, tmp[it].y));
        }
#pragma unroll
        for (int it = 0; it < 20; ++it) {
          int idx = tid + it*256; int b = idx/80, j = idx - b*80;
          panA[b*SW + 80 + j] = (_Float16)tf[it];
        }
      }
      __syncthreads();
      gemm_phase<KW,PH,SW>(panA, wf, u, 320, b0, acc);
    } else {
      // K-order: [wv(77) x(3) hin(400) | hrec(400)]; pairs: ff 0..239, rec 0..199
      poll1(p.flags, (L==2) ? 1 : 2, t, (L==2) ? TF1 : TF2);
      if (L == 3 && t >= 64) poll1(p.flags, 4, t-64, 1);
      __syncthreads();
      // ph0 stage (ff pairs 0..109)
      {
        u32 tmp[28];
#pragma unroll
        for (int it = 0; it < 28; ++it) {
          int idx = tid + it*256; if (idx >= 64*110) break;
          int b = idx/110, pl = idx - b*110;
          tmp[it] = ldc_u(ffin + ((size_t)t*64 + b)*240 + pl);
        }
#pragma unroll
        for (int it = 0; it < 28; ++it) {
          int idx = tid + it*256; if (idx >= 64*110) break;
          int b = idx/110, pl = idx - b*110;
          *(u32*)(panA + b*SW + 2*pl) = tmp[it];
        }
      }
      __syncthreads();
      // ph1 stage (ff 110..219) || compute ph0
      {
        u32 tmp[28];
#pragma unroll
        for (int it = 0; it < 28; ++it) {
          int idx = tid + it*256; if (idx >= 64*110) break;
          int b = idx/110, pl = idx - b*110;
          tmp[it] = ldc_u(ffin + ((size_t)t*64 + b)*240 + 110 + pl);
        }
        gemm_phase<KW,PH,SW>(panA, wf, u, 0, b0, acc);
#pragma unroll
        for (int it = 0; it < 28; ++it) {
          int idx = tid + it*256; if (idx >= 64*110) break;
          int b = idx/110, pl = idx - b*110;
          *(u32*)(panB + b*SW + 2*pl) = tmp[it];
        }
      }
      if (t > 0) poll1(p.flags, STG, t-1, (L==2) ? TF2 : TF3);  // own stage t-1
      __syncthreads();
      // ph2 stage (ff 220..239 + rec pairs 0..89) || compute ph1
      {
        u32 tmp[28];
#pragma unroll
        for (int it = 0; it < 28; ++it) {
          int idx = tid + it*256; if (idx >= 64*110) break;
          int b = idx/110, pl = idx - b*110;
          u32 pv;
          if (pl < 20) pv = ldc_u(ffin + ((size_t)t*64 + b)*240 + 220 + pl);
          else {
            float2 f = ldc_f2(hsrc + (size_t)b*400 + 2*(pl-20));
            pv = h2u(pk16(f.x, f.y));
          }
          tmp[it] = pv;
        }
        gemm_phase<KW,PH,SW>(panB, wf, u, 220, b0, acc);
#pragma unroll
        for (int it = 0; it < 28; ++it) {
          int idx = tid + it*256; if (idx >= 64*110) break;
          int b = idx/110, pl = idx - b*110;
          *(u32*)(panA + b*SW + 2*pl) = tmp[it];
        }
      }
      __syncthreads();
      // ph3 stage (rec pairs 90..199) || compute ph2
      {
        u32 tmp[28];
#pragma unroll
        for (int it = 0; it < 28; ++it) {
          int idx = tid + it*256; if (idx >= 64*110) break;
          int b = idx/110, pl = idx - b*110;
          float2 f = ldc_f2(hsrc + (size_t)b*400 + 180 + 2*pl);
          tmp[it] = h2u(pk16(f.x, f.y));
        }
        gemm_phase<KW,PH,SW>(panA, wf, u, 440, b0, acc);
#pragma unroll
        for (int it = 0; it < 28; ++it) {
          int idx = tid + it*256; if (idx >= 64*110) break;
          int b = idx/110, pl = idx - b*110;
          *(u32*)(panB + b*SW + 2*pl) = tmp[it];
        }
      }
      __syncthreads();
      gemm_phase<KW,PH,SW>(panB, wf, u, 660, b0, acc);
    }

    // ---- cell update (in-register) ----
    float hn[2];
#pragma unroll
    for (int r = 0; r < 2; ++r) {
      float gi = acc[r][0]+bsum[0], gf = acc[r][1]+bsum[1];
      float gg = acc[r][2]+bsum[2], go = acc[r][3]+bsum[3];
      float cn = sigm(gf)*creg[r] + sigm(gi)*tanhf(gg);
      creg[r] = cn;
      hn[r] = sigm(go)*tanhf(cn);
      stc_f(hsL + (size_t)par*B_*H_ + (size_t)(b0+r)*H_ + u, hn[r]);
    }
    __syncthreads();   // protect ex reuse vs prior iteration reads
    ex[b0*8 + cg] = hn[0];
    ex[(b0+1)*8 + cg] = hn[1];
    __syncthreads();
    {
      int b = tid >> 2, j = tid & 3;
      h2 hp = pk16(ex[b*8 + 2*j], ex[b*8 + 2*j + 1]);
      if (L == 1)      stpk(p.ff2 + ((size_t)t*64 + b)*240 + 40 + wg*4 + j, hp);
      else if (L == 2) stpk(p.ff3 + ((size_t)t*64 + b)*240 + 40 + wg*4 + j, hp);
      else             stpk(p.h3r + ((size_t)(t&63)*64 + b)*200 + wg*4 + j, hp);
    }
    __syncthreads();
    set_flag(p.flags, STG, t);
  }
}

// ================= attention stage: 8 wgs x 8 batches =================
__device__ void pa_role(const P& p, int pa, char* smem_raw) {
  const int tid = threadIdx.x;
  const int b0p = pa*8;
  float* hsm  = (float*)smem_raw;             // 8*400
  float* mixs = hsm + 3200;                   // 240
  float* kaps = mixs + 240;                   // 80
  float* phis = kaps + 80;                    // 400
  float* wvs  = phis + 400;                   // 616
  float kap_reg = 0.f;
  if (tid < 80) kap_reg = p.pkap[(size_t)(b0p + tid/10)*10 + (tid % 10)];

  for (int t = 0; t < T_; ++t) {
    poll1(p.flags, 0, t, TF0);
    __syncthreads();
    for (int idx = tid; idx < 1600; idx += 256) {
      int bl = idx / 200, pp = idx - bl*200;
      float2 f2 = ldc_f2(p.hs1 + (size_t)(t&1)*B_*H_ + (size_t)(b0p+bl)*400 + 2*pp);
      *(float2*)(hsm + bl*400 + 2*pp) = f2;
    }
    __syncthreads();
    if (tid < 240) {
      int bl = tid / 30, m = tid - (tid/30)*30;
      const float* hr = hsm + bl*400;
      const float* wrow = p.wwin + (size_t)m*400;
      float d = 0.f;
#pragma unroll 5
      for (int k = 0; k < 400; k += 4) {
        float4 hv = *(const float4*)(hr + k);
        float4 w4 = *(const float4*)(wrow + k);
        d += hv.x*w4.x + hv.y*w4.y + hv.z*w4.z + hv.w*w4.w;
      }
      mixs[tid] = __expf(d + p.bwin[m]);
    }
    __syncthreads();
    if (tid < 80) {
      int bl = tid/10, kk = tid - (tid/10)*10;
      kap_reg += mixs[bl*30 + 20 + kk];
      kaps[bl*10 + kk] = kap_reg;
      if (t == T_-1) stc_f(p.out_kap + (size_t)(b0p+bl)*10 + kk, kap_reg);
    }
    __syncthreads();
    for (int i = tid; i < 400; i += 256) {
      int bl = i / 50, uu = i - (i/50)*50;
      float s = 0.f; const float fu = (float)uu;
#pragma unroll
      for (int k = 0; k < 10; ++k) {
        float df = kaps[bl*10+k] - fu;
        s += mixs[bl*30+k] * __expf(-mixs[bl*30+10+k]*df*df);
      }
      phis[i] = s * p.tmask[(size_t)(b0p+bl)*50 + uu];
    }
    for (int i = tid; i < 616; i += 256) wvs[i] = 0.f;
    __syncthreads();
    if (tid < 8) {
      int b = b0p + tid;
      for (int uu = 0; uu < 50; ++uu)
        wvs[tid*77 + p.text[(size_t)b*50 + uu]] += phis[tid*50 + uu];
    }
    __syncthreads();
    // fp32 wv output (+ L1 consumption)
    for (int i = tid; i < 616; i += 256) {
      int bl = i / 77, v = i - (i/77)*77;
      stc_f(p.out_wv + ((size_t)(b0p+bl)*600 + t)*77 + v, wvs[i]);
    }
    // f16 pairs [wv(77) x(3)] -> ff2 & ff3 pairs 0..39
    for (int i = tid; i < 8*40; i += 256) {
      int bl = i / 40, pr = i - bl*40;
      int b = b0p + bl;
      float f0, f1;
      if (pr < 38)      { f0 = wvs[bl*77 + 2*pr]; f1 = wvs[bl*77 + 2*pr + 1]; }
      else if (pr == 38){ f0 = wvs[bl*77 + 76];   f1 = p.x[((size_t)b*600 + t)*3 + 0]; }
      else              { f0 = p.x[((size_t)b*600 + t)*3 + 1]; f1 = p.x[((size_t)b*600 + t)*3 + 2]; }
      h2 hp = pk16(f0, f1);
      stpk(p.ff2 + ((size_t)t*64 + b)*240 + pr, hp);
      stpk(p.ff3 + ((size_t)t*64 + b)*240 + pr, hp);
    }
    __syncthreads();
    set_flag(p.flags, 1, t);
  }
}

// ================= output projection: 8 wgs, t-interleaved =================
__device__ void out_role(const P& p, int g, char* smem_raw) {
  const int tid = threadIdx.x;
  const int cg = tid & 31, bg = tid >> 5;
  const int c0 = cg*4;
  _Float16* pan = (_Float16*)smem_raw;
  // one-time wout f16 repack into this wg's PRIVATE copy (writer==reader,
  // same-CU coherent; cross-wg plain-memory sharing is NOT XCD-coherent).
  _Float16* wofg = p.wof + (size_t)g*WOFCOPY;
  for (int e = tid; e < 121*1200; e += 256)
    wofg[e] = (_Float16)p.wout[e];
  float bo[4]; const _Float16* wrp[4];
#pragma unroll
  for (int j = 0; j < 4; ++j) {
    int c = c0 + j; if (c > 120) c = 120;
    wrp[j] = wofg + (size_t)c*1200;
    bo[j] = p.bout[c];
  }
  __syncthreads();

  for (int t = g; t < T_; t += GOUT) {
    poll1(p.flags, 3, t, TF3);
    __syncthreads();
    float acc[8][4];
#pragma unroll
    for (int r = 0; r < 8; ++r)
#pragma unroll
      for (int j = 0; j < 4; ++j) acc[r][j] = 0.f;

    for (int ph = 0; ph < 5; ++ph) {
      // stage 120 pairs: P in [120ph, 120ph+120)
      for (int idx = tid; idx < 64*120; idx += 256) {
        int b = idx / 120, pl = idx - b*120;
        int Pp = ph*120 + pl;
        u32 pv;
        if (Pp < 200)      pv = ldc_u(p.ff2 + ((size_t)t*64 + b)*240 + 40 + Pp);
        else if (Pp < 400) pv = ldc_u(p.ff3 + ((size_t)t*64 + b)*240 + 40 + (Pp-200));
        else               pv = ldc_u(p.h3r + ((size_t)(t&63)*64 + b)*200 + (Pp-400));
        *(u32*)(pan + b*SWO + 2*pl) = pv;
      }
      __syncthreads();
      const int kbase = ph*240;
#pragma unroll 3
      for (int k = 0; k < 240; k += 4) {
        h4 w4[4];
#pragma unroll
        for (int j = 0; j < 4; ++j) w4[j] = *(const h4*)(wrp[j] + kbase + k);
#pragma unroll
        for (int r = 0; r < 8; ++r) {
          h4 a = *(const h4*)(pan + (bg*8+r)*SWO + k);
          h2 al = lo4(a), ah = hi4(a);
#pragma unroll
          for (int j = 0; j < 4; ++j) {
            acc[r][j] = dot2(al, lo4(w4[j]), acc[r][j]);
            acc[r][j] = dot2(ah, hi4(w4[j]), acc[r][j]);
          }
        }
      }
      __syncthreads();
    }
#pragma unroll
    for (int r = 0; r < 8; ++r)
#pragma unroll
      for (int j = 0; j < 4; ++j) {
        int c = c0 + j;
        if (c < 121)
          p.out_y[((size_t)(bg*8+r)*600 + t)*121 + c] = acc[r][j] + bo[j];
      }
    __syncthreads();
    set_flag(p.flags, 4, t);
  }
}

__global__ __launch_bounds__(256) void hw_pipeline(P p) {
  __shared__ __align__(16) char smem_raw[SMEM_BYTES];
  const int bid = blockIdx.x;
  if (bid < G1) lstm_role<1>(p, bid, smem_raw);
  else if (bid < G1+GPA) pa_role(p, bid - G1, smem_raw);
  else if (bid < G1+GPA+G2) lstm_role<2>(p, bid - G1 - GPA, smem_raw);
  else if (bid < G1+GPA+G2+G3) lstm_role<3>(p, bid - G1 - GPA - G2, smem_raw);
  else out_role(p, bid - G1 - GPA - G2 - G3, smem_raw);
}

extern "C" void kernel_launch(void* const* d_in, const int* in_sizes, int n_in,
                              void* d_out, int out_size, void* d_ws, size_t ws_size,
                              hipStream_t stream) {
  (void)in_sizes; (void)n_in; (void)out_size; (void)ws_size;
  P p;
  p.x = (const float*)d_in[0];
  p.text = (const int*)d_in[1];
  p.tmask = (const float*)d_in[2];
  p.h0 = (const float*)d_in[3];
  p.c0 = (const float*)d_in[4];
  p.pwv = (const float*)d_in[5];
  p.pkap = (const float*)d_in[6];
  p.wih1 = (const float*)d_in[7];  p.whh1 = (const float*)d_in[8];
  p.bih1 = (const float*)d_in[9];  p.bhh1 = (const float*)d_in[10];
  p.wih2 = (const float*)d_in[11]; p.whh2 = (const float*)d_in[12];
  p.bih2 = (const float*)d_in[13]; p.bhh2 = (const float*)d_in[14];
  p.wih3 = (const float*)d_in[15]; p.whh3 = (const float*)d_in[16];
  p.bih3 = (const float*)d_in[17]; p.bhh3 = (const float*)d_in[18];
  p.wwin = (const float*)d_in[19]; p.bwin = (const float*)d_in[20];
  p.wout = (const float*)d_in[21]; p.bout = (const float*)d_in[22];
  float* out = (float*)d_out;
  p.out_y  = out;
  p.out_wv = out + (size_t)B_*T_*OUT_;
  p.out_kap = p.out_wv + (size_t)B_*T_*V_;
  char* ws = (char*)d_ws;
  p.flags = (int*)(ws + FLAGS_B);
  p.hs1 = (float*)(ws + HS1_B);
  p.hs2 = (float*)(ws + HS2_B);
  p.hs3 = (float*)(ws + HS3_B);
  p.w1f = (_Float16*)(ws + W1F_B);
  p.w2f = (_Float16*)(ws + W2F_B);
  p.w3f = (_Float16*)(ws + W3F_B);
  p.wof = (_Float16*)(ws + WOF_B);
  p.ff2 = (u32*)(ws + FF2_B);
  p.ff3 = (u32*)(ws + FF3_B);
  p.h3r = (u32*)(ws + H3R_B);
  (void)hipMemsetAsync(ws + FLAGS_B, 0, FLAGS_SZ, stream);
  hipLaunchKernelGGL(hw_pipeline, dim3(NBLK), dim3(256), 0, stream, p);
}

// Round 6
// 25827.621 us; speedup vs baseline: 3.3284x; 1.0444x over previous
//
#include <hip/hip_runtime.h>
#include <hip/hip_bf16.h>
#include <cstdint>
#include <cstddef>
#include <cstring>

using u32 = unsigned int;
using u64 = unsigned long long;
typedef _Float16 h2 __attribute__((ext_vector_type(2)));
typedef _Float16 h4 __attribute__((ext_vector_type(4)));

constexpr int B_=64, T_=600, U_=50, H_=400, V_=77, K_=10, OUT_=121;
constexpr int G1=50, GPA=8, G2=50, G3=50, GOUT=8;
constexpr int NBLK = G1+GPA+G2+G3+GOUT; // 166

// flag targets
constexpr int TF0=G1, TF1=GPA, TF2=G2, TF3=G3;

// ---- ws byte offsets ----
constexpr size_t FLAGS_B = 0;                       // 5*600 counters, 128B stride
constexpr size_t FLAGS_SZ = 5ull*600*32*4;          // 384000
constexpr size_t HS1_B = 384000;                    // [2][64][400] fp32 ping-pong
constexpr size_t HSSZ  = 2ull*B_*H_*4;              // 204800
constexpr size_t HS2_B = HS1_B + HSSZ;
constexpr size_t HS3_B = HS2_B + HSSZ;
// interleaved f16 weights, per-wg regions: [kk][cu8][g4][h4] (256B per kk)
constexpr size_t W1F_B = HS3_B + HSSZ;              // 50 * (480/4)*128 f16
constexpr size_t W1WG  = 120ull*128;                // f16 per wg
constexpr size_t W2F_B = W1F_B + 50ull*W1WG*2;
constexpr size_t W2WG  = 220ull*128;
constexpr size_t W3F_B = W2F_B + 50ull*W2WG*2;
constexpr size_t WOF_B = W3F_B + 50ull*W2WG*2;      // 8 * [kk300][cg32][c4][h4]
constexpr size_t WOWG  = 300ull*32*16;              // f16 per wg copy
constexpr size_t WWT_B = WOF_B + 8ull*WOWG*2;       // 8 * [k400][m32] fp32
constexpr size_t WWTWG = 400ull*32;
constexpr size_t FF2_B = ((WWT_B + 8ull*WWTWG*4 + 255)/256)*256; // u32 [600][64][240]
constexpr size_t FFSZ  = 600ull*64*240*4;
constexpr size_t FF3_B = FF2_B + FFSZ;
constexpr size_t H3R_B = FF3_B + FFSZ;              // u32 [64][64][200] ring
// total ~89 MB

// LDS layout
constexpr int SW2 = 228;   // f16 stride, L2/L3 phase panel (220 dims)
constexpr int SW1 = 164;   // L1 (160 dims)
constexpr int SWO = 244;   // OUT (240 dims)
constexpr int EXOFF = 58368;  // fp32 exchange 64x8
constexpr int SMEM_BYTES = 60416;

struct P {
  const float *x, *tmask, *h0, *c0, *pwv, *pkap;
  const int *text;
  const float *wih1,*whh1,*bih1,*bhh1;
  const float *wih2,*whh2,*bih2,*bhh2;
  const float *wih3,*whh3,*bih3,*bhh3;
  const float *wwin,*bwin,*wout,*bout;
  float *out_y,*out_wv,*out_kap;
  float *hs1,*hs2,*hs3,*wwt;
  _Float16 *w1f,*w2f,*w3f,*wof;
  u32 *ff2,*ff3,*h3r;
  int *flags;
};

// ---- coherent (agent-scope) helpers ----
__device__ __forceinline__ float ldc_f(const float* p) {
  return __hip_atomic_load((float*)p, __ATOMIC_RELAXED, __HIP_MEMORY_SCOPE_AGENT);
}
__device__ __forceinline__ void stc_f(float* p, float v) {
  __hip_atomic_store(p, v, __ATOMIC_RELAXED, __HIP_MEMORY_SCOPE_AGENT);
}
__device__ __forceinline__ u32 ldc_u(const u32* p) {
  return __hip_atomic_load((u32*)p, __ATOMIC_RELAXED, __HIP_MEMORY_SCOPE_AGENT);
}
__device__ __forceinline__ void stc_u(u32* p, u32 v) {
  __hip_atomic_store(p, v, __ATOMIC_RELAXED, __HIP_MEMORY_SCOPE_AGENT);
}
__device__ __forceinline__ float2 ldc_f2(const float* p) {
  u64 x = __hip_atomic_load((u64*)p, __ATOMIC_RELAXED, __HIP_MEMORY_SCOPE_AGENT);
  float2 r; memcpy(&r, &x, 8); return r;
}
__device__ __forceinline__ float sigm(float x) { return 1.f/(1.f+__expf(-x)); }
__device__ __forceinline__ h2 pk16(float a, float b) {
  auto t = __builtin_amdgcn_cvt_pkrtz(a, b);
  h2 r; memcpy(&r, &t, 4); return r;
}
__device__ __forceinline__ u32 h2u(h2 v) { u32 r; memcpy(&r, &v, 4); return r; }
__device__ __forceinline__ void stpk(u32* dst, h2 v) { stc_u(dst, h2u(v)); }
__device__ __forceinline__ float dot2(h2 a, h2 b, float c) { return __builtin_amdgcn_fdot2(a, b, c, false); }
__device__ __forceinline__ h2 lo4(h4 v) { return __builtin_shufflevector(v, v, 0, 1); }
__device__ __forceinline__ h2 hi4(h4 v) { return __builtin_shufflevector(v, v, 2, 3); }

__device__ __forceinline__ void poll1(int* flags, int stage, int t, int target) {
  if (threadIdx.x == 0) {
    int* f = flags + ((size_t)stage*600 + t)*32;
    while (__hip_atomic_load(f, __ATOMIC_RELAXED, __HIP_MEMORY_SCOPE_AGENT) < target) {}
  }
}
__device__ __forceinline__ void set_flag(int* flags, int stage, int t) {
  if (threadIdx.x == 0)
    __hip_atomic_fetch_add(flags + ((size_t)stage*600 + t)*32, 1,
                           __ATOMIC_RELAXED, __HIP_MEMORY_SCOPE_AGENT);
}

// gemm phase, interleaved weights: thread owns unit cu (4 gates), batches b0,b0+1
// wgW layout: [kk][cu8][g4][h4] -> per kk, thread reads 32 consecutive bytes.
template<int PH, int SW>
__device__ __forceinline__ void gemm_phase(const _Float16* pan, const _Float16* wgW,
                                           int cu, int kbase, int b0, float acc[2][4]) {
  const _Float16* a0 = pan + b0*SW;
  const _Float16* a1 = a0 + SW;
  const _Float16* wp = wgW + ((size_t)(kbase >> 2) * 8 + cu) * 16;
#pragma unroll 5
  for (int k = 0; k < PH; k += 4) {
    h4 x0 = *(const h4*)(a0+k), x1 = *(const h4*)(a1+k);
    h4 wa = *(const h4*)(wp);
    h4 wb = *(const h4*)(wp+4);
    h4 wc = *(const h4*)(wp+8);
    h4 wd = *(const h4*)(wp+12);
    wp += 128;
    h2 x0l=lo4(x0), x0h=hi4(x0), x1l=lo4(x1), x1h=hi4(x1);
    acc[0][0]=dot2(x0l,lo4(wa),acc[0][0]); acc[0][0]=dot2(x0h,hi4(wa),acc[0][0]);
    acc[0][1]=dot2(x0l,lo4(wb),acc[0][1]); acc[0][1]=dot2(x0h,hi4(wb),acc[0][1]);
    acc[0][2]=dot2(x0l,lo4(wc),acc[0][2]); acc[0][2]=dot2(x0h,hi4(wc),acc[0][2]);
    acc[0][3]=dot2(x0l,lo4(wd),acc[0][3]); acc[0][3]=dot2(x0h,hi4(wd),acc[0][3]);
    acc[1][0]=dot2(x1l,lo4(wa),acc[1][0]); acc[1][0]=dot2(x1h,hi4(wa),acc[1][0]);
    acc[1][1]=dot2(x1l,lo4(wb),acc[1][1]); acc[1][1]=dot2(x1h,hi4(wb),acc[1][1]);
    acc[1][2]=dot2(x1l,lo4(wc),acc[1][2]); acc[1][2]=dot2(x1h,hi4(wc),acc[1][2]);
    acc[1][3]=dot2(x1l,lo4(wd),acc[1][3]); acc[1][3]=dot2(x1h,hi4(wd),acc[1][3]);
  }
}

// ================= LSTM stage template =================
template <int L>
__device__ void lstm_role(const P& p, int wg, char* smem_raw) {
  const int tid = threadIdx.x;
  constexpr int KW = (L==1) ? 480 : 880;
  constexpr int PH = (L==1) ? 160 : 220;
  constexpr int SW = (L==1) ? SW1 : SW2;
  constexpr int STG = (L==1) ? 0 : (L==2) ? 2 : 3;
  constexpr size_t WWG = (L==1) ? W1WG : W2WG;
  const int cg = tid & 7, tb = tid >> 3;
  const int u  = wg*8 + cg;
  const int b0 = tb*2;
  _Float16* wf = (L==1) ? p.w1f : (L==2) ? p.w2f : p.w3f;
  _Float16* wgW = wf + (size_t)wg * WWG;
  const float* wih = (L==1) ? p.wih1 : (L==2) ? p.wih2 : p.wih3;
  const float* whh = (L==1) ? p.whh1 : (L==2) ? p.whh2 : p.whh3;
  const float* bih = (L==1) ? p.bih1 : (L==2) ? p.bih2 : p.bih3;
  const float* bhh = (L==1) ? p.bhh1 : (L==2) ? p.bhh2 : p.bhh3;
  float* hsL = (L==1) ? p.hs1 : (L==2) ? p.hs2 : p.hs3;
  const u32* ffin = (L==3) ? p.ff3 : p.ff2;
  _Float16* panA = (_Float16*)smem_raw;
  _Float16* panB = panA + 64*SW;
  float* ex = (float*)(smem_raw + EXOFF);

  // ---- one-time interleaved f16 weight repack (own region; same-wg wr->rd) ----
  for (int e = tid; e < 32*KW; e += 256) {
    int lr = e / KW, j = e - lr*KW;
    int g = lr >> 3, cu = lr & 7;
    int r = g*400 + wg*8 + cu;
    float v;
    if (L == 1) {
      if (j < 400)      v = whh[(size_t)r*400 + j];
      else if (j < 477) v = wih[(size_t)r*80 + 3 + (j-400)];
      else              v = wih[(size_t)r*80 + (j-477)];
    } else {
      if (j < 77)       v = wih[(size_t)r*480 + 403 + j];
      else if (j < 80)  v = wih[(size_t)r*480 + (j-77)];
      else if (j < 480) v = wih[(size_t)r*480 + 3 + (j-80)];
      else              v = whh[(size_t)r*400 + (j-480)];
    }
    int kk = j >> 2, kc = j & 3;
    wgW[((size_t)kk*8 + cu)*16 + g*4 + kc] = (_Float16)v;
  }
  float bsum[4];
#pragma unroll
  for (int g = 0; g < 4; ++g) bsum[g] = bih[g*400+u] + bhh[g*400+u];
  float creg[2];
  creg[0] = p.c0[(size_t)(L-1)*B_*H_ + (size_t)b0*H_ + u];
  creg[1] = p.c0[(size_t)(L-1)*B_*H_ + (size_t)(b0+1)*H_ + u];
  __syncthreads();

  for (int t = 0; t < T_; ++t) {
    const int par = t & 1;
    const float* hsrc = (t == 0) ? (p.h0 + (size_t)(L-1)*B_*H_)
                                 : (hsL + (size_t)(par^1)*B_*H_);
    float acc[2][4] = {{0,0,0,0},{0,0,0,0}};

    if (L == 1) {
      // K-order: [h1rec(400) | wv(77) x(3)]
      if (t > 0) poll1(p.flags, 0, t-1, TF0);
      __syncthreads();
      {
        float2 tmp[20];
#pragma unroll
        for (int it = 0; it < 20; ++it) {
          int idx = tid + it*256; int b = idx/80, pl = idx - b*80;
          tmp[it] = ldc_f2(hsrc + (size_t)b*400 + 2*pl);
        }
#pragma unroll
        for (int it = 0; it < 20; ++it) {
          int idx = tid + it*256; int b = idx/80, pl = idx - b*80;
          *(u32*)(panA + b*SW + 2*pl) = h2u(pk16(tmp[it].x, tmp[it].y));
        }
      }
      __syncthreads();
      {
        float2 tmp[20];
#pragma unroll
        for (int it = 0; it < 20; ++it) {
          int idx = tid + it*256; int b = idx/80, pl = idx - b*80;
          tmp[it] = ldc_f2(hsrc + (size_t)b*400 + 160 + 2*pl);
        }
        gemm_phase<PH,SW>(panA, wgW, cg, 0, b0, acc);
#pragma unroll
        for (int it = 0; it < 20; ++it) {
          int idx = tid + it*256; int b = idx/80, pl = idx - b*80;
          *(u32*)(panB + b*SW + 2*pl) = h2u(pk16(tmp[it].x, tmp[it].y));
        }
      }
      if (t > 0) poll1(p.flags, 1, t-1, TF1);
      __syncthreads();
      {
        float2 tmp[10];
#pragma unroll
        for (int it = 0; it < 10; ++it) {
          int idx = tid + it*256; int b = idx/40, pl = idx - b*40;
          tmp[it] = ldc_f2(hsrc + (size_t)b*400 + 320 + 2*pl);
        }
        float tf[20];
#pragma unroll
        for (int it = 0; it < 20; ++it) {
          int idx = tid + it*256; int b = idx/80, j = idx - b*80;
          float v;
          if (j < 77) v = (t == 0) ? p.pwv[(size_t)b*77 + j]
                                   : ldc_f(p.out_wv + ((size_t)b*600 + (t-1))*77 + j);
          else v = p.x[((size_t)b*600 + t)*3 + (j-77)];
          tf[it] = v;
        }
        gemm_phase<PH,SW>(panB, wgW, cg, 160, b0, acc);
#pragma unroll
        for (int it = 0; it < 10; ++it) {
          int idx = tid + it*256; int b = idx/40, pl = idx - b*40;
          *(u32*)(panA + b*SW + 2*pl) = h2u(pk16(tmp[it].x, tmp[it].y));
        }
#pragma unroll
        for (int it = 0; it < 20; ++it) {
          int idx = tid + it*256; int b = idx/80, j = idx - b*80;
          panA[b*SW + 80 + j] = (_Float16)tf[it];
        }
      }
      __syncthreads();
      gemm_phase<PH,SW>(panA, wgW, cg, 320, b0, acc);
    } else {
      // K-order: [wv(77) x(3) hin(400) | hrec(400)]
      poll1(p.flags, (L==2) ? 1 : 2, t, (L==2) ? TF1 : TF2);
      if (L == 3 && t >= 64) poll1(p.flags, 4, t-64, 1);
      __syncthreads();
      {
        u32 tmp[28];
#pragma unroll
        for (int it = 0; it < 28; ++it) {
          int idx = tid + it*256; if (idx >= 64*110) break;
          int b = idx/110, pl = idx - b*110;
          tmp[it] = ldc_u(ffin + ((size_t)t*64 + b)*240 + pl);
        }
#pragma unroll
        for (int it = 0; it < 28; ++it) {
          int idx = tid + it*256; if (idx >= 64*110) break;
          int b = idx/110, pl = idx - b*110;
          *(u32*)(panA + b*SW + 2*pl) = tmp[it];
        }
      }
      __syncthreads();
      {
        u32 tmp[28];
#pragma unroll
        for (int it = 0; it < 28; ++it) {
          int idx = tid + it*256; if (idx >= 64*110) break;
          int b = idx/110, pl = idx - b*110;
          tmp[it] = ldc_u(ffin + ((size_t)t*64 + b)*240 + 110 + pl);
        }
        gemm_phase<PH,SW>(panA, wgW, cg, 0, b0, acc);
#pragma unroll
        for (int it = 0; it < 28; ++it) {
          int idx = tid + it*256; if (idx >= 64*110) break;
          int b = idx/110, pl = idx - b*110;
          *(u32*)(panB + b*SW + 2*pl) = tmp[it];
        }
      }
      if (t > 0) poll1(p.flags, STG, t-1, (L==2) ? TF2 : TF3);
      __syncthreads();
      {
        u32 tmp[28];
#pragma unroll
        for (int it = 0; it < 28; ++it) {
          int idx = tid + it*256; if (idx >= 64*110) break;
          int b = idx/110, pl = idx - b*110;
          u32 pv;
          if (pl < 20) pv = ldc_u(ffin + ((size_t)t*64 + b)*240 + 220 + pl);
          else {
            float2 f = ldc_f2(hsrc + (size_t)b*400 + 2*(pl-20));
            pv = h2u(pk16(f.x, f.y));
          }
          tmp[it] = pv;
        }
        gemm_phase<PH,SW>(panB, wgW, cg, 220, b0, acc);
#pragma unroll
        for (int it = 0; it < 28; ++it) {
          int idx = tid + it*256; if (idx >= 64*110) break;
          int b = idx/110, pl = idx - b*110;
          *(u32*)(panA + b*SW + 2*pl) = tmp[it];
        }
      }
      __syncthreads();
      {
        u32 tmp[28];
#pragma unroll
        for (int it = 0; it < 28; ++it) {
          int idx = tid + it*256; if (idx >= 64*110) break;
          int b = idx/110, pl = idx - b*110;
          float2 f = ldc_f2(hsrc + (size_t)b*400 + 180 + 2*pl);
          tmp[it] = h2u(pk16(f.x, f.y));
        }
        gemm_phase<PH,SW>(panA, wgW, cg, 440, b0, acc);
#pragma unroll
        for (int it = 0; it < 28; ++it) {
          int idx = tid + it*256; if (idx >= 64*110) break;
          int b = idx/110, pl = idx - b*110;
          *(u32*)(panB + b*SW + 2*pl) = tmp[it];
        }
      }
      __syncthreads();
      gemm_phase<PH,SW>(panB, wgW, cg, 660, b0, acc);
    }

    // ---- cell update (in-register) ----
    float hn[2];
#pragma unroll
    for (int r = 0; r < 2; ++r) {
      float gi = acc[r][0]+bsum[0], gf = acc[r][1]+bsum[1];
      float gg = acc[r][2]+bsum[2], go = acc[r][3]+bsum[3];
      float cn = sigm(gf)*creg[r] + sigm(gi)*tanhf(gg);
      creg[r] = cn;
      hn[r] = sigm(go)*tanhf(cn);
      stc_f(hsL + (size_t)par*B_*H_ + (size_t)(b0+r)*H_ + u, hn[r]);
    }
    __syncthreads();
    ex[b0*8 + cg] = hn[0];
    ex[(b0+1)*8 + cg] = hn[1];
    __syncthreads();
    {
      int b = tid >> 2, j = tid & 3;
      h2 hp = pk16(ex[b*8 + 2*j], ex[b*8 + 2*j + 1]);
      if (L == 1)      stpk(p.ff2 + ((size_t)t*64 + b)*240 + 40 + wg*4 + j, hp);
      else if (L == 2) stpk(p.ff3 + ((size_t)t*64 + b)*240 + 40 + wg*4 + j, hp);
      else             stpk(p.h3r + ((size_t)(t&63)*64 + b)*200 + wg*4 + j, hp);
    }
    __syncthreads();
    set_flag(p.flags, STG, t);
  }
}

// ================= attention stage: 8 wgs x 8 batches =================
__device__ void pa_role(const P& p, int pa, char* smem_raw) {
  const int tid = threadIdx.x;
  const int b0p = pa*8;
  float* hsm  = (float*)smem_raw;             // 8*400
  float* mixs = hsm + 3200;                   // 240
  float* kaps = mixs + 240;                   // 80
  float* phis = kaps + 80;                    // 400
  float* wvs  = phis + 400;                   // 616
  float kap_reg = 0.f;
  if (tid < 80) kap_reg = p.pkap[(size_t)(b0p + tid/10)*10 + (tid % 10)];
  // one-time k-major transpose of wwin into this wg's private copy
  float* wwT = p.wwt + (size_t)pa*WWTWG;
  for (int e = tid; e < 400*30; e += 256) {
    int k = e / 30, m = e - (e/30)*30;
    wwT[k*32 + m] = p.wwin[(size_t)m*400 + k];
  }

  for (int t = 0; t < T_; ++t) {
    poll1(p.flags, 0, t, TF0);
    __syncthreads();
    for (int idx = tid; idx < 1600; idx += 256) {
      int bl = idx / 200, pp = idx - bl*200;
      float2 f2 = ldc_f2(p.hs1 + (size_t)(t&1)*B_*H_ + (size_t)(b0p+bl)*400 + 2*pp);
      *(float2*)(hsm + bl*400 + 2*pp) = f2;
    }
    __syncthreads();
    if (tid < 240) {
      int bl = tid / 30, m = tid - (tid/30)*30;
      const float* hr = hsm + bl*400;
      float d = 0.f;
#pragma unroll 4
      for (int k = 0; k < 400; ++k) d += hr[k] * wwT[k*32 + m];
      mixs[tid] = __expf(d + p.bwin[m]);
    }
    __syncthreads();
    if (tid < 80) {
      int bl = tid/10, kk = tid - (tid/10)*10;
      kap_reg += mixs[bl*30 + 20 + kk];
      kaps[bl*10 + kk] = kap_reg;
      if (t == T_-1) stc_f(p.out_kap + (size_t)(b0p+bl)*10 + kk, kap_reg);
    }
    __syncthreads();
    for (int i = tid; i < 400; i += 256) {
      int bl = i / 50, uu = i - (i/50)*50;
      float s = 0.f; const float fu = (float)uu;
#pragma unroll
      for (int k = 0; k < 10; ++k) {
        float df = kaps[bl*10+k] - fu;
        s += mixs[bl*30+k] * __expf(-mixs[bl*30+10+k]*df*df);
      }
      phis[i] = s * p.tmask[(size_t)(b0p+bl)*50 + uu];
    }
    for (int i = tid; i < 616; i += 256) wvs[i] = 0.f;
    __syncthreads();
    if (tid < 8) {
      int b = b0p + tid;
      for (int uu = 0; uu < 50; ++uu)
        wvs[tid*77 + p.text[(size_t)b*50 + uu]] += phis[tid*50 + uu];
    }
    __syncthreads();
    for (int i = tid; i < 616; i += 256) {
      int bl = i / 77, v = i - (i/77)*77;
      stc_f(p.out_wv + ((size_t)(b0p+bl)*600 + t)*77 + v, wvs[i]);
    }
    for (int i = tid; i < 8*40; i += 256) {
      int bl = i / 40, pr = i - bl*40;
      int b = b0p + bl;
      float f0, f1;
      if (pr < 38)      { f0 = wvs[bl*77 + 2*pr]; f1 = wvs[bl*77 + 2*pr + 1]; }
      else if (pr == 38){ f0 = wvs[bl*77 + 76];   f1 = p.x[((size_t)b*600 + t)*3 + 0]; }
      else              { f0 = p.x[((size_t)b*600 + t)*3 + 1]; f1 = p.x[((size_t)b*600 + t)*3 + 2]; }
      h2 hp = pk16(f0, f1);
      stpk(p.ff2 + ((size_t)t*64 + b)*240 + pr, hp);
      stpk(p.ff3 + ((size_t)t*64 + b)*240 + pr, hp);
    }
    __syncthreads();
    set_flag(p.flags, 1, t);
  }
}

// ================= output projection: 8 wgs, t-interleaved =================
__device__ void out_role(const P& p, int g, char* smem_raw) {
  const int tid = threadIdx.x;
  const int cg = tid & 31, bg = tid >> 5;
  const int c0 = cg*4;
  _Float16* pan = (_Float16*)smem_raw;
  // one-time interleaved wout repack: [kk][cg32][c4][h4], private per wg
  _Float16* wofg = p.wof + (size_t)g*WOWG;
  for (int e = tid; e < 300*32*16; e += 256) {
    int kk = e >> 9, rem = e & 511;
    int cgi = rem >> 4, j4 = rem & 15;
    int j = j4 >> 2, kc = j4 & 3;
    int c = cgi*4 + j; if (c > 120) c = 120;
    wofg[e] = (_Float16)p.wout[(size_t)c*1200 + kk*4 + kc];
  }
  float bo[4];
#pragma unroll
  for (int j = 0; j < 4; ++j) {
    int c = c0 + j; if (c > 120) c = 120;
    bo[j] = p.bout[c];
  }
  __syncthreads();

  for (int t = g; t < T_; t += GOUT) {
    poll1(p.flags, 3, t, TF3);
    __syncthreads();
    float acc[8][4];
#pragma unroll
    for (int r = 0; r < 8; ++r)
#pragma unroll
      for (int j = 0; j < 4; ++j) acc[r][j] = 0.f;

    for (int ph = 0; ph < 5; ++ph) {
      for (int idx = tid; idx < 64*120; idx += 256) {
        int b = idx / 120, pl = idx - b*120;
        int Pp = ph*120 + pl;
        u32 pv;
        if (Pp < 200)      pv = ldc_u(p.ff2 + ((size_t)t*64 + b)*240 + 40 + Pp);
        else if (Pp < 400) pv = ldc_u(p.ff3 + ((size_t)t*64 + b)*240 + 40 + (Pp-200));
        else               pv = ldc_u(p.h3r + ((size_t)(t&63)*64 + b)*200 + (Pp-400));
        *(u32*)(pan + b*SWO + 2*pl) = pv;
      }
      __syncthreads();
      const _Float16* wp = wofg + ((size_t)(ph*60)*32 + cg)*16;
#pragma unroll 3
      for (int k = 0; k < 240; k += 4) {
        h4 wa = *(const h4*)(wp);
        h4 wb = *(const h4*)(wp+4);
        h4 wc = *(const h4*)(wp+8);
        h4 wd = *(const h4*)(wp+12);
        wp += 512;
#pragma unroll
        for (int r = 0; r < 8; ++r) {
          h4 a = *(const h4*)(pan + (bg*8+r)*SWO + k);
          h2 al = lo4(a), ah = hi4(a);
          acc[r][0] = dot2(al, lo4(wa), acc[r][0]); acc[r][0] = dot2(ah, hi4(wa), acc[r][0]);
          acc[r][1] = dot2(al, lo4(wb), acc[r][1]); acc[r][1] = dot2(ah, hi4(wb), acc[r][1]);
          acc[r][2] = dot2(al, lo4(wc), acc[r][2]); acc[r][2] = dot2(ah, hi4(wc), acc[r][2]);
          acc[r][3] = dot2(al, lo4(wd), acc[r][3]); acc[r][3] = dot2(ah, hi4(wd), acc[r][3]);
        }
      }
      __syncthreads();
    }
#pragma unroll
    for (int r = 0; r < 8; ++r)
#pragma unroll
      for (int j = 0; j < 4; ++j) {
        int c = c0 + j;
        if (c < 121)
          p.out_y[((size_t)(bg*8+r)*600 + t)*121 + c] = acc[r][j] + bo[j];
      }
    __syncthreads();
    set_flag(p.flags, 4, t);
  }
}

__global__ __launch_bounds__(256) void hw_pipeline(P p) {
  __shared__ __align__(16) char smem_raw[SMEM_BYTES];
  const int bid = blockIdx.x;
  if (bid < G1) lstm_role<1>(p, bid, smem_raw);
  else if (bid < G1+GPA) pa_role(p, bid - G1, smem_raw);
  else if (bid < G1+GPA+G2) lstm_role<2>(p, bid - G1 - GPA, smem_raw);
  else if (bid < G1+GPA+G2+G3) lstm_role<3>(p, bid - G1 - GPA - G2, smem_raw);
  else out_role(p, bid - G1 - GPA - G2 - G3, smem_raw);
}

extern "C" void kernel_launch(void* const* d_in, const int* in_sizes, int n_in,
                              void* d_out, int out_size, void* d_ws, size_t ws_size,
                              hipStream_t stream) {
  (void)in_sizes; (void)n_in; (void)out_size; (void)ws_size;
  P p;
  p.x = (const float*)d_in[0];
  p.text = (const int*)d_in[1];
  p.tmask = (const float*)d_in[2];
  p.h0 = (const float*)d_in[3];
  p.c0 = (const float*)d_in[4];
  p.pwv = (const float*)d_in[5];
  p.pkap = (const float*)d_in[6];
  p.wih1 = (const float*)d_in[7];  p.whh1 = (const float*)d_in[8];
  p.bih1 = (const float*)d_in[9];  p.bhh1 = (const float*)d_in[10];
  p.wih2 = (const float*)d_in[11]; p.whh2 = (const float*)d_in[12];
  p.bih2 = (const float*)d_in[13]; p.bhh2 = (const float*)d_in[14];
  p.wih3 = (const float*)d_in[15]; p.whh3 = (const float*)d_in[16];
  p.bih3 = (const float*)d_in[17]; p.bhh3 = (const float*)d_in[18];
  p.wwin = (const float*)d_in[19]; p.bwin = (const float*)d_in[20];
  p.wout = (const float*)d_in[21]; p.bout = (const float*)d_in[22];
  float* out = (float*)d_out;
  p.out_y  = out;
  p.out_wv = out + (size_t)B_*T_*OUT_;
  p.out_kap = p.out_wv + (size_t)B_*T_*V_;
  char* ws = (char*)d_ws;
  p.flags = (int*)(ws + FLAGS_B);
  p.hs1 = (float*)(ws + HS1_B);
  p.hs2 = (float*)(ws + HS2_B);
  p.hs3 = (float*)(ws + HS3_B);
  p.w1f = (_Float16*)(ws + W1F_B);
  p.w2f = (_Float16*)(ws + W2F_B);
  p.w3f = (_Float16*)(ws + W3F_B);
  p.wof = (_Float16*)(ws + WOF_B);
  p.wwt = (float*)(ws + WWT_B);
  p.ff2 = (u32*)(ws + FF2_B);
  p.ff3 = (u32*)(ws + FF3_B);
  p.h3r = (u32*)(ws + H3R_B);
  (void)hipMemsetAsync(ws + FLAGS_B, 0, FLAGS_SZ, stream);
  hipLaunchKernelGGL(hw_pipeline, dim3(NBLK), dim3(256), 0, stream, p);
}

// Round 7
// 25393.051 us; speedup vs baseline: 3.3854x; 1.0171x over previous
//
#include <hip/hip_runtime.h>
#include <hip/hip_bf16.h>
#include <cstdint>
#include <cstddef>
#include <cstring>

using u32 = unsigned int;
using u64 = unsigned long long;
typedef _Float16 h2 __attribute__((ext_vector_type(2)));
typedef _Float16 h4 __attribute__((ext_vector_type(4)));

constexpr int B_=64, T_=600, U_=50, V_=77, H_=400, OUT_=121;
constexpr int G1=50, GPA=8, G2=50, G3=50, GOUT=8;
constexpr int NBLK = G1+GPA+G2+G3+GOUT; // 166

// flag targets (producer counts)
constexpr int TF0=G1, TF1=GPA, TF2=G2, TF3=G3;

// ---- ws byte offsets ----
// flags: per-producer 16B slots: [stage5][t600][prod64] * 16B
constexpr size_t FLAGS_B = 0;
constexpr size_t FLAGS_SZ = 5ull*600*64*16;         // 3,072,000
constexpr size_t HS1_B = 3072256;                   // [2][64][400] fp32 ping-pong
constexpr size_t HSSZ  = 2ull*B_*H_*4;              // 204800
constexpr size_t HS2_B = HS1_B + HSSZ;
constexpr size_t HS3_B = HS2_B + HSSZ;
// interleaved f16 weights, per-wg regions: [kk][cu8][g4][h4] (256B per kk)
constexpr size_t W1F_B = HS3_B + HSSZ;              // 50 * (480/4)*128 f16
constexpr size_t W1WG  = 120ull*128;                // f16 per wg
constexpr size_t W2F_B = W1F_B + 50ull*W1WG*2;
constexpr size_t W2WG  = 220ull*128;
constexpr size_t W3F_B = W2F_B + 50ull*W2WG*2;
constexpr size_t WOF_B = W3F_B + 50ull*W2WG*2;      // 8 * [kk300][cg32][c4][h4]
constexpr size_t WOWG  = 300ull*32*16;              // f16 per wg copy
constexpr size_t WWT_B = WOF_B + 8ull*WOWG*2;       // 8 * [k400][m32] fp32
constexpr size_t WWTWG = 400ull*32;
constexpr size_t FF2_B = ((WWT_B + 8ull*WWTWG*4 + 255)/256)*256; // u32 [600][64][240]
constexpr size_t FFSZ  = 600ull*64*240*4;
constexpr size_t FF3_B = FF2_B + FFSZ;
constexpr size_t H3R_B = FF3_B + FFSZ;              // u32 [64][64][200] ring
// total ~92 MB

// LDS layout
constexpr int SW2 = 228;   // f16 stride, L2/L3 phase panel (220 dims)
constexpr int SW1 = 164;   // L1 (160 dims)
constexpr int SWO = 244;   // OUT (240 dims)
constexpr int EXOFF = 58368;  // fp32 exchange 64x8
constexpr int SMEM_BYTES = 60416;

struct P {
  const float *x, *tmask, *h0, *c0, *pwv, *pkap;
  const int *text;
  const float *wih1,*whh1,*bih1,*bhh1;
  const float *wih2,*whh2,*bih2,*bhh2;
  const float *wih3,*whh3,*bih3,*bhh3;
  const float *wwin,*bwin,*wout,*bout;
  float *out_y,*out_wv,*out_kap;
  float *hs1,*hs2,*hs3,*wwt;
  _Float16 *w1f,*w2f,*w3f,*wof;
  u32 *ff2,*ff3,*h3r;
  u32 *flags;
};

// ---- coherent (agent-scope) helpers ----
__device__ __forceinline__ float ldc_f(const float* p) {
  return __hip_atomic_load((float*)p, __ATOMIC_RELAXED, __HIP_MEMORY_SCOPE_AGENT);
}
__device__ __forceinline__ void stc_f(float* p, float v) {
  __hip_atomic_store(p, v, __ATOMIC_RELAXED, __HIP_MEMORY_SCOPE_AGENT);
}
__device__ __forceinline__ u32 ldc_u(const u32* p) {
  return __hip_atomic_load((u32*)p, __ATOMIC_RELAXED, __HIP_MEMORY_SCOPE_AGENT);
}
__device__ __forceinline__ void stc_u(u32* p, u32 v) {
  __hip_atomic_store(p, v, __ATOMIC_RELAXED, __HIP_MEMORY_SCOPE_AGENT);
}
__device__ __forceinline__ float2 ldc_f2(const float* p) {
  u64 x = __hip_atomic_load((u64*)p, __ATOMIC_RELAXED, __HIP_MEMORY_SCOPE_AGENT);
  float2 r; memcpy(&r, &x, 8); return r;
}
__device__ __forceinline__ float sigm(float x) { return 1.f/(1.f+__expf(-x)); }
__device__ __forceinline__ h2 pk16(float a, float b) {
  auto t = __builtin_amdgcn_cvt_pkrtz(a, b);
  h2 r; memcpy(&r, &t, 4); return r;
}
__device__ __forceinline__ u32 h2u(h2 v) { u32 r; memcpy(&r, &v, 4); return r; }
__device__ __forceinline__ void stpk(u32* dst, h2 v) { stc_u(dst, h2u(v)); }
__device__ __forceinline__ float dot2(h2 a, h2 b, float c) { return __builtin_amdgcn_fdot2(a, b, c, false); }
__device__ __forceinline__ h2 lo4(h4 v) { return __builtin_shufflevector(v, v, 0, 1); }
__device__ __forceinline__ h2 hi4(h4 v) { return __builtin_shufflevector(v, v, 2, 3); }

// ---- per-producer flag slots: store (no RMW) + parallel poll ----
__device__ __forceinline__ void poll_all(u32* flags, int stage, int t, int n) {
  const size_t base = ((size_t)stage*600 + t) * 64;
  for (int i = threadIdx.x; i < n; i += 256) {
    const u32* s = flags + ((base + i) << 2);   // 16B slot stride
    while (ldc_u(s) == 0) {}
  }
}
__device__ __forceinline__ void set_flag(u32* flags, int stage, int t, int prod) {
  // caller guarantees __syncthreads() (vmcnt drained) precedes this
  if (threadIdx.x == 0)
    stc_u(flags + ((((size_t)stage*600 + t)*64 + prod) << 2), 1u);
}

// gemm phase, interleaved weights: thread owns unit cu (4 gates), batches b0,b0+1
// wgW layout: [kk][cu8][g4][h4] -> per kk, thread reads 32 consecutive bytes.
template<int PH, int SW>
__device__ __forceinline__ void gemm_phase(const _Float16* pan, const _Float16* wgW,
                                           int cu, int kbase, int b0, float acc[2][4]) {
  const _Float16* a0 = pan + b0*SW;
  const _Float16* a1 = a0 + SW;
  const _Float16* wp = wgW + ((size_t)(kbase >> 2) * 8 + cu) * 16;
#pragma unroll 5
  for (int k = 0; k < PH; k += 4) {
    h4 x0 = *(const h4*)(a0+k), x1 = *(const h4*)(a1+k);
    h4 wa = *(const h4*)(wp);
    h4 wb = *(const h4*)(wp+4);
    h4 wc = *(const h4*)(wp+8);
    h4 wd = *(const h4*)(wp+12);
    wp += 128;
    h2 x0l=lo4(x0), x0h=hi4(x0), x1l=lo4(x1), x1h=hi4(x1);
    acc[0][0]=dot2(x0l,lo4(wa),acc[0][0]); acc[0][0]=dot2(x0h,hi4(wa),acc[0][0]);
    acc[0][1]=dot2(x0l,lo4(wb),acc[0][1]); acc[0][1]=dot2(x0h,hi4(wb),acc[0][1]);
    acc[0][2]=dot2(x0l,lo4(wc),acc[0][2]); acc[0][2]=dot2(x0h,hi4(wc),acc[0][2]);
    acc[0][3]=dot2(x0l,lo4(wd),acc[0][3]); acc[0][3]=dot2(x0h,hi4(wd),acc[0][3]);
    acc[1][0]=dot2(x1l,lo4(wa),acc[1][0]); acc[1][0]=dot2(x1h,hi4(wa),acc[1][0]);
    acc[1][1]=dot2(x1l,lo4(wb),acc[1][1]); acc[1][1]=dot2(x1h,hi4(wb),acc[1][1]);
    acc[1][2]=dot2(x1l,lo4(wc),acc[1][2]); acc[1][2]=dot2(x1h,hi4(wc),acc[1][2]);
    acc[1][3]=dot2(x1l,lo4(wd),acc[1][3]); acc[1][3]=dot2(x1h,hi4(wd),acc[1][3]);
  }
}

// ================= LSTM stage template =================
template <int L>
__device__ void lstm_role(const P& p, int wg, char* smem_raw) {
  const int tid = threadIdx.x;
  constexpr int KW = (L==1) ? 480 : 880;
  constexpr int PH = (L==1) ? 160 : 220;
  constexpr int SW = (L==1) ? SW1 : SW2;
  constexpr int STG = (L==1) ? 0 : (L==2) ? 2 : 3;
  constexpr size_t WWG = (L==1) ? W1WG : W2WG;
  const int cg = tid & 7, tb = tid >> 3;
  const int u  = wg*8 + cg;
  const int b0 = tb*2;
  _Float16* wf = (L==1) ? p.w1f : (L==2) ? p.w2f : p.w3f;
  _Float16* wgW = wf + (size_t)wg * WWG;
  const float* wih = (L==1) ? p.wih1 : (L==2) ? p.wih2 : p.wih3;
  const float* whh = (L==1) ? p.whh1 : (L==2) ? p.whh2 : p.whh3;
  const float* bih = (L==1) ? p.bih1 : (L==2) ? p.bih2 : p.bih3;
  const float* bhh = (L==1) ? p.bhh1 : (L==2) ? p.bhh2 : p.bhh3;
  float* hsL = (L==1) ? p.hs1 : (L==2) ? p.hs2 : p.hs3;
  const u32* ffin = (L==3) ? p.ff3 : p.ff2;
  _Float16* panA = (_Float16*)smem_raw;
  _Float16* panB = panA + 64*SW;
  float* ex = (float*)(smem_raw + EXOFF);

  // ---- one-time interleaved f16 weight repack (own region; same-wg wr->rd) ----
  for (int e = tid; e < 32*KW; e += 256) {
    int lr = e / KW, j = e - lr*KW;
    int g = lr >> 3, cu = lr & 7;
    int r = g*400 + wg*8 + cu;
    float v;
    if (L == 1) {
      if (j < 400)      v = whh[(size_t)r*400 + j];
      else if (j < 477) v = wih[(size_t)r*80 + 3 + (j-400)];
      else              v = wih[(size_t)r*80 + (j-477)];
    } else {
      if (j < 77)       v = wih[(size_t)r*480 + 403 + j];
      else if (j < 80)  v = wih[(size_t)r*480 + (j-77)];
      else if (j < 480) v = wih[(size_t)r*480 + 3 + (j-80)];
      else              v = whh[(size_t)r*400 + (j-480)];
    }
    int kk = j >> 2, kc = j & 3;
    wgW[((size_t)kk*8 + cu)*16 + g*4 + kc] = (_Float16)v;
  }
  float bsum[4];
#pragma unroll
  for (int g = 0; g < 4; ++g) bsum[g] = bih[g*400+u] + bhh[g*400+u];
  float creg[2];
  creg[0] = p.c0[(size_t)(L-1)*B_*H_ + (size_t)b0*H_ + u];
  creg[1] = p.c0[(size_t)(L-1)*B_*H_ + (size_t)(b0+1)*H_ + u];
  __syncthreads();

  for (int t = 0; t < T_; ++t) {
    const int par = t & 1;
    const float* hsrc = (t == 0) ? (p.h0 + (size_t)(L-1)*B_*H_)
                                 : (hsL + (size_t)(par^1)*B_*H_);
    float acc[2][4] = {{0,0,0,0},{0,0,0,0}};

    if (L == 1) {
      // K-order: [h1rec(400) | wv(77) x(3)]
      if (t > 0) poll_all(p.flags, 0, t-1, TF0);
      __syncthreads();
      {
        float2 tmp[20];
#pragma unroll
        for (int it = 0; it < 20; ++it) {
          int idx = tid + it*256; int b = idx/80, pl = idx - b*80;
          tmp[it] = ldc_f2(hsrc + (size_t)b*400 + 2*pl);
        }
#pragma unroll
        for (int it = 0; it < 20; ++it) {
          int idx = tid + it*256; int b = idx/80, pl = idx - b*80;
          *(u32*)(panA + b*SW + 2*pl) = h2u(pk16(tmp[it].x, tmp[it].y));
        }
      }
      __syncthreads();
      {
        float2 tmp[20];
#pragma unroll
        for (int it = 0; it < 20; ++it) {
          int idx = tid + it*256; int b = idx/80, pl = idx - b*80;
          tmp[it] = ldc_f2(hsrc + (size_t)b*400 + 160 + 2*pl);
        }
        gemm_phase<PH,SW>(panA, wgW, cg, 0, b0, acc);
#pragma unroll
        for (int it = 0; it < 20; ++it) {
          int idx = tid + it*256; int b = idx/80, pl = idx - b*80;
          *(u32*)(panB + b*SW + 2*pl) = h2u(pk16(tmp[it].x, tmp[it].y));
        }
      }
      if (t > 0) poll_all(p.flags, 1, t-1, TF1);
      __syncthreads();
      {
        float2 tmp[10];
#pragma unroll
        for (int it = 0; it < 10; ++it) {
          int idx = tid + it*256; int b = idx/40, pl = idx - b*40;
          tmp[it] = ldc_f2(hsrc + (size_t)b*400 + 320 + 2*pl);
        }
        float tf[20];
#pragma unroll
        for (int it = 0; it < 20; ++it) {
          int idx = tid + it*256; int b = idx/80, j = idx - b*80;
          float v;
          if (j < 77) v = (t == 0) ? p.pwv[(size_t)b*77 + j]
                                   : ldc_f(p.out_wv + ((size_t)b*600 + (t-1))*77 + j);
          else v = p.x[((size_t)b*600 + t)*3 + (j-77)];
          tf[it] = v;
        }
        gemm_phase<PH,SW>(panB, wgW, cg, 160, b0, acc);
#pragma unroll
        for (int it = 0; it < 10; ++it) {
          int idx = tid + it*256; int b = idx/40, pl = idx - b*40;
          *(u32*)(panA + b*SW + 2*pl) = h2u(pk16(tmp[it].x, tmp[it].y));
        }
#pragma unroll
        for (int it = 0; it < 20; ++it) {
          int idx = tid + it*256; int b = idx/80, j = idx - b*80;
          panA[b*SW + 80 + j] = (_Float16)tf[it];
        }
      }
      __syncthreads();
      gemm_phase<PH,SW>(panA, wgW, cg, 320, b0, acc);
    } else {
      // K-order: [wv(77) x(3) hin(400) | hrec(400)]
      poll_all(p.flags, (L==2) ? 1 : 2, t, (L==2) ? TF1 : TF2);
      if (L == 3 && t >= 64) poll_all(p.flags, 4, t-64, 1);
      __syncthreads();
      {
        u32 tmp[28];
#pragma unroll
        for (int it = 0; it < 28; ++it) {
          int idx = tid + it*256; if (idx >= 64*110) break;
          int b = idx/110, pl = idx - b*110;
          tmp[it] = ldc_u(ffin + ((size_t)t*64 + b)*240 + pl);
        }
#pragma unroll
        for (int it = 0; it < 28; ++it) {
          int idx = tid + it*256; if (idx >= 64*110) break;
          int b = idx/110, pl = idx - b*110;
          *(u32*)(panA + b*SW + 2*pl) = tmp[it];
        }
      }
      __syncthreads();
      {
        u32 tmp[28];
#pragma unroll
        for (int it = 0; it < 28; ++it) {
          int idx = tid + it*256; if (idx >= 64*110) break;
          int b = idx/110, pl = idx - b*110;
          tmp[it] = ldc_u(ffin + ((size_t)t*64 + b)*240 + 110 + pl);
        }
        gemm_phase<PH,SW>(panA, wgW, cg, 0, b0, acc);
#pragma unroll
        for (int it = 0; it < 28; ++it) {
          int idx = tid + it*256; if (idx >= 64*110) break;
          int b = idx/110, pl = idx - b*110;
          *(u32*)(panB + b*SW + 2*pl) = tmp[it];
        }
      }
      if (t > 0) poll_all(p.flags, STG, t-1, (L==2) ? TF2 : TF3);
      __syncthreads();
      {
        u32 tmp[28];
#pragma unroll
        for (int it = 0; it < 28; ++it) {
          int idx = tid + it*256; if (idx >= 64*110) break;
          int b = idx/110, pl = idx - b*110;
          u32 pv;
          if (pl < 20) pv = ldc_u(ffin + ((size_t)t*64 + b)*240 + 220 + pl);
          else {
            float2 f = ldc_f2(hsrc + (size_t)b*400 + 2*(pl-20));
            pv = h2u(pk16(f.x, f.y));
          }
          tmp[it] = pv;
        }
        gemm_phase<PH,SW>(panB, wgW, cg, 220, b0, acc);
#pragma unroll
        for (int it = 0; it < 28; ++it) {
          int idx = tid + it*256; if (idx >= 64*110) break;
          int b = idx/110, pl = idx - b*110;
          *(u32*)(panA + b*SW + 2*pl) = tmp[it];
        }
      }
      __syncthreads();
      {
        u32 tmp[28];
#pragma unroll
        for (int it = 0; it < 28; ++it) {
          int idx = tid + it*256; if (idx >= 64*110) break;
          int b = idx/110, pl = idx - b*110;
          float2 f = ldc_f2(hsrc + (size_t)b*400 + 180 + 2*pl);
          tmp[it] = h2u(pk16(f.x, f.y));
        }
        gemm_phase<PH,SW>(panA, wgW, cg, 440, b0, acc);
#pragma unroll
        for (int it = 0; it < 28; ++it) {
          int idx = tid + it*256; if (idx >= 64*110) break;
          int b = idx/110, pl = idx - b*110;
          *(u32*)(panB + b*SW + 2*pl) = tmp[it];
        }
      }
      __syncthreads();
      gemm_phase<PH,SW>(panB, wgW, cg, 660, b0, acc);
    }

    // ---- cell update (in-register) ----
    float hn[2];
#pragma unroll
    for (int r = 0; r < 2; ++r) {
      float gi = acc[r][0]+bsum[0], gf = acc[r][1]+bsum[1];
      float gg = acc[r][2]+bsum[2], go = acc[r][3]+bsum[3];
      float cn = sigm(gf)*creg[r] + sigm(gi)*tanhf(gg);
      creg[r] = cn;
      hn[r] = sigm(go)*tanhf(cn);
      stc_f(hsL + (size_t)par*B_*H_ + (size_t)(b0+r)*H_ + u, hn[r]);
    }
    __syncthreads();
    ex[b0*8 + cg] = hn[0];
    ex[(b0+1)*8 + cg] = hn[1];
    __syncthreads();
    {
      int b = tid >> 2, j = tid & 3;
      h2 hp = pk16(ex[b*8 + 2*j], ex[b*8 + 2*j + 1]);
      if (L == 1)      stpk(p.ff2 + ((size_t)t*64 + b)*240 + 40 + wg*4 + j, hp);
      else if (L == 2) stpk(p.ff3 + ((size_t)t*64 + b)*240 + 40 + wg*4 + j, hp);
      else             stpk(p.h3r + ((size_t)(t&63)*64 + b)*200 + wg*4 + j, hp);
    }
    __syncthreads();
    set_flag(p.flags, STG, t, wg);
  }
}

// ================= attention stage: 8 wgs x 8 batches =================
__device__ void pa_role(const P& p, int pa, char* smem_raw) {
  const int tid = threadIdx.x;
  const int b0p = pa*8;
  float* hsm  = (float*)smem_raw;             // 8*400
  float* mixs = hsm + 3200;                   // 240
  float* kaps = mixs + 240;                   // 80
  float* phis = kaps + 80;                    // 400
  float* wvs  = phis + 400;                   // 616
  float kap_reg = 0.f;
  if (tid < 80) kap_reg = p.pkap[(size_t)(b0p + tid/10)*10 + (tid % 10)];
  // one-time k-major transpose of wwin into this wg's private copy
  float* wwT = p.wwt + (size_t)pa*WWTWG;
  for (int e = tid; e < 400*30; e += 256) {
    int k = e / 30, m = e - (e/30)*30;
    wwT[k*32 + m] = p.wwin[(size_t)m*400 + k];
  }

  for (int t = 0; t < T_; ++t) {
    poll_all(p.flags, 0, t, TF0);
    __syncthreads();
    for (int idx = tid; idx < 1600; idx += 256) {
      int bl = idx / 200, pp = idx - bl*200;
      float2 f2 = ldc_f2(p.hs1 + (size_t)(t&1)*B_*H_ + (size_t)(b0p+bl)*400 + 2*pp);
      *(float2*)(hsm + bl*400 + 2*pp) = f2;
    }
    __syncthreads();
    if (tid < 240) {
      int bl = tid / 30, m = tid - (tid/30)*30;
      const float* hr = hsm + bl*400;
      float d0=0.f, d1=0.f, d2=0.f, d3=0.f;
#pragma unroll 4
      for (int k = 0; k < 400; k += 4) {
        d0 += hr[k]   * wwT[(k)*32   + m];
        d1 += hr[k+1] * wwT[(k+1)*32 + m];
        d2 += hr[k+2] * wwT[(k+2)*32 + m];
        d3 += hr[k+3] * wwT[(k+3)*32 + m];
      }
      mixs[tid] = __expf((d0+d1)+(d2+d3) + p.bwin[m]);
    }
    __syncthreads();
    if (tid < 80) {
      int bl = tid/10, kk = tid - (tid/10)*10;
      kap_reg += mixs[bl*30 + 20 + kk];
      kaps[bl*10 + kk] = kap_reg;
      if (t == T_-1) stc_f(p.out_kap + (size_t)(b0p+bl)*10 + kk, kap_reg);
    }
    __syncthreads();
    for (int i = tid; i < 400; i += 256) {
      int bl = i / 50, uu = i - (i/50)*50;
      float s = 0.f; const float fu = (float)uu;
#pragma unroll
      for (int k = 0; k < 10; ++k) {
        float df = kaps[bl*10+k] - fu;
        s += mixs[bl*30+k] * __expf(-mixs[bl*30+10+k]*df*df);
      }
      phis[i] = s * p.tmask[(size_t)(b0p+bl)*50 + uu];
    }
    for (int i = tid; i < 616; i += 256) wvs[i] = 0.f;
    __syncthreads();
    if (tid < 8) {
      int b = b0p + tid;
      for (int uu = 0; uu < 50; ++uu)
        wvs[tid*77 + p.text[(size_t)b*50 + uu]] += phis[tid*50 + uu];
    }
    __syncthreads();
    for (int i = tid; i < 616; i += 256) {
      int bl = i / 77, v = i - (i/77)*77;
      stc_f(p.out_wv + ((size_t)(b0p+bl)*600 + t)*77 + v, wvs[i]);
    }
    for (int i = tid; i < 8*40; i += 256) {
      int bl = i / 40, pr = i - bl*40;
      int b = b0p + bl;
      float f0, f1;
      if (pr < 38)      { f0 = wvs[bl*77 + 2*pr]; f1 = wvs[bl*77 + 2*pr + 1]; }
      else if (pr == 38){ f0 = wvs[bl*77 + 76];   f1 = p.x[((size_t)b*600 + t)*3 + 0]; }
      else              { f0 = p.x[((size_t)b*600 + t)*3 + 1]; f1 = p.x[((size_t)b*600 + t)*3 + 2]; }
      h2 hp = pk16(f0, f1);
      stpk(p.ff2 + ((size_t)t*64 + b)*240 + pr, hp);
      stpk(p.ff3 + ((size_t)t*64 + b)*240 + pr, hp);
    }
    __syncthreads();
    set_flag(p.flags, 1, t, pa);
  }
}

// ================= output projection: 8 wgs, t-interleaved =================
__device__ void out_role(const P& p, int g, char* smem_raw) {
  const int tid = threadIdx.x;
  const int cg = tid & 31, bg = tid >> 5;
  const int c0 = cg*4;
  _Float16* pan = (_Float16*)smem_raw;
  // one-time interleaved wout repack: [kk][cg32][c4][h4], private per wg
  _Float16* wofg = p.wof + (size_t)g*WOWG;
  for (int e = tid; e < 300*32*16; e += 256) {
    int kk = e >> 9, rem = e & 511;
    int cgi = rem >> 4, j4 = rem & 15;
    int j = j4 >> 2, kc = j4 & 3;
    int c = cgi*4 + j; if (c > 120) c = 120;
    wofg[e] = (_Float16)p.wout[(size_t)c*1200 + kk*4 + kc];
  }
  float bo[4];
#pragma unroll
  for (int j = 0; j < 4; ++j) {
    int c = c0 + j; if (c > 120) c = 120;
    bo[j] = p.bout[c];
  }
  __syncthreads();

  for (int t = g; t < T_; t += GOUT) {
    poll_all(p.flags, 3, t, TF3);
    __syncthreads();
    float acc[8][4];
#pragma unroll
    for (int r = 0; r < 8; ++r)
#pragma unroll
      for (int j = 0; j < 4; ++j) acc[r][j] = 0.f;

    for (int ph = 0; ph < 5; ++ph) {
      for (int idx = tid; idx < 64*120; idx += 256) {
        int b = idx / 120, pl = idx - b*120;
        int Pp = ph*120 + pl;
        u32 pv;
        if (Pp < 200)      pv = ldc_u(p.ff2 + ((size_t)t*64 + b)*240 + 40 + Pp);
        else if (Pp < 400) pv = ldc_u(p.ff3 + ((size_t)t*64 + b)*240 + 40 + (Pp-200));
        else               pv = ldc_u(p.h3r + ((size_t)(t&63)*64 + b)*200 + (Pp-400));
        *(u32*)(pan + b*SWO + 2*pl) = pv;
      }
      __syncthreads();
      const _Float16* wp = wofg + ((size_t)(ph*60)*32 + cg)*16;
#pragma unroll 3
      for (int k = 0; k < 240; k += 4) {
        h4 wa = *(const h4*)(wp);
        h4 wb = *(const h4*)(wp+4);
        h4 wc = *(const h4*)(wp+8);
        h4 wd = *(const h4*)(wp+12);
        wp += 512;
#pragma unroll
        for (int r = 0; r < 8; ++r) {
          h4 a = *(const h4*)(pan + (bg*8+r)*SWO + k);
          h2 al = lo4(a), ah = hi4(a);
          acc[r][0] = dot2(al, lo4(wa), acc[r][0]); acc[r][0] = dot2(ah, hi4(wa), acc[r][0]);
          acc[r][1] = dot2(al, lo4(wb), acc[r][1]); acc[r][1] = dot2(ah, hi4(wb), acc[r][1]);
          acc[r][2] = dot2(al, lo4(wc), acc[r][2]); acc[r][2] = dot2(ah, hi4(wc), acc[r][2]);
          acc[r][3] = dot2(al, lo4(wd), acc[r][3]); acc[r][3] = dot2(ah, hi4(wd), acc[r][3]);
        }
      }
      __syncthreads();
    }
#pragma unroll
    for (int r = 0; r < 8; ++r)
#pragma unroll
      for (int j = 0; j < 4; ++j) {
        int c = c0 + j;
        if (c < 121)
          p.out_y[((size_t)(bg*8+r)*600 + t)*121 + c] = acc[r][j] + bo[j];
      }
    __syncthreads();
    set_flag(p.flags, 4, t, 0);
  }
}

__global__ __launch_bounds__(256) void hw_pipeline(P p) {
  __shared__ __align__(16) char smem_raw[SMEM_BYTES];
  const int bid = blockIdx.x;
  if (bid < G1) lstm_role<1>(p, bid, smem_raw);
  else if (bid < G1+GPA) pa_role(p, bid - G1, smem_raw);
  else if (bid < G1+GPA+G2) lstm_role<2>(p, bid - G1 - GPA, smem_raw);
  else if (bid < G1+GPA+G2+G3) lstm_role<3>(p, bid - G1 - GPA - G2, smem_raw);
  else out_role(p, bid - G1 - GPA - G2 - G3, smem_raw);
}

extern "C" void kernel_launch(void* const* d_in, const int* in_sizes, int n_in,
                              void* d_out, int out_size, void* d_ws, size_t ws_size,
                              hipStream_t stream) {
  (void)in_sizes; (void)n_in; (void)out_size; (void)ws_size;
  P p;
  p.x = (const float*)d_in[0];
  p.text = (const int*)d_in[1];
  p.tmask = (const float*)d_in[2];
  p.h0 = (const float*)d_in[3];
  p.c0 = (const float*)d_in[4];
  p.pwv = (const float*)d_in[5];
  p.pkap = (const float*)d_in[6];
  p.wih1 = (const float*)d_in[7];  p.whh1 = (const float*)d_in[8];
  p.bih1 = (const float*)d_in[9];  p.bhh1 = (const float*)d_in[10];
  p.wih2 = (const float*)d_in[11]; p.whh2 = (const float*)d_in[12];
  p.bih2 = (const float*)d_in[13]; p.bhh2 = (const float*)d_in[14];
  p.wih3 = (const float*)d_in[15]; p.whh3 = (const float*)d_in[16];
  p.bih3 = (const float*)d_in[17]; p.bhh3 = (const float*)d_in[18];
  p.wwin = (const float*)d_in[19]; p.bwin = (const float*)d_in[20];
  p.wout = (const float*)d_in[21]; p.bout = (const float*)d_in[22];
  float* out = (float*)d_out;
  p.out_y  = out;
  p.out_wv = out + (size_t)B_*T_*OUT_;
  p.out_kap = p.out_wv + (size_t)B_*T_*V_;
  char* ws = (char*)d_ws;
  p.flags = (u32*)(ws + FLAGS_B);
  p.hs1 = (float*)(ws + HS1_B);
  p.hs2 = (float*)(ws + HS2_B);
  p.hs3 = (float*)(ws + HS3_B);
  p.w1f = (_Float16*)(ws + W1F_B);
  p.w2f = (_Float16*)(ws + W2F_B);
  p.w3f = (_Float16*)(ws + W3F_B);
  p.wof = (_Float16*)(ws + WOF_B);
  p.wwt = (float*)(ws + WWT_B);
  p.ff2 = (u32*)(ws + FF2_B);
  p.ff3 = (u32*)(ws + FF3_B);
  p.h3r = (u32*)(ws + H3R_B);
  (void)hipMemsetAsync(ws + FLAGS_B, 0, FLAGS_SZ, stream);
  hipLaunchKernelGGL(hw_pipeline, dim3(NBLK), dim3(256), 0, stream, p);
}